// Round 1
// baseline (2318.928 us; speedup 1.0000x reference)
//
#include <hip/hip_runtime.h>
#include <hip/hip_bf16.h>
#include <math.h>

// ---------------- problem constants ----------------
#define D_MODEL 1024
#define D_STATE 16
#define D_CONV  4
#define D_INNER 2048
#define DT_RANK 64
#define LSEQ    1024

// ---------------- tiled fp32 GEMM ----------------
// C[m,n] = sum_k A[m*K+k] * B(k,n)
//   BNT=true : B is (N,K) row-major  -> B[n*K+k]   (dot of rows)
//   BNT=false: B is (K,N) row-major  -> B[k*N+n]   (optionally + B2)
// storeT=0: C[m*N+n]; storeT=1: C[n*M+m]
constexpr int TS = 64;
constexpr int KT = 16;

template<bool BNT>
__global__ __launch_bounds__(256)
void sgemm_k(const float* __restrict__ A, const float* __restrict__ B,
             const float* __restrict__ B2, float* __restrict__ C,
             int M, int N, int K, int storeT)
{
    __shared__ float As[KT][TS];
    __shared__ float Bs[KT][TS];
    const int tid = threadIdx.x;
    const int tx = tid & 15, ty = tid >> 4;
    const int mBase = blockIdx.y * TS;
    const int nBase = blockIdx.x * TS;

    float acc[4][4] = {};

    const int ar = tid >> 2;        // 0..63 row within tile
    const int ak = (tid & 3) * 4;   // 0,4,8,12

    for (int kb = 0; kb < K; kb += KT) {
        // ---- stage A (M,K) row-major, transposed into As[k][m]
        {
            const int gm = mBase + ar;
            float4 av = make_float4(0.f, 0.f, 0.f, 0.f);
            if (gm < M) av = *(const float4*)&A[(size_t)gm * K + kb + ak];
            As[ak + 0][ar] = av.x;
            As[ak + 1][ar] = av.y;
            As[ak + 2][ar] = av.z;
            As[ak + 3][ar] = av.w;
        }
        // ---- stage B
        if (BNT) {
            const int gn = nBase + ar;
            float4 bv = make_float4(0.f, 0.f, 0.f, 0.f);
            if (gn < N) bv = *(const float4*)&B[(size_t)gn * K + kb + ak];
            Bs[ak + 0][ar] = bv.x;
            Bs[ak + 1][ar] = bv.y;
            Bs[ak + 2][ar] = bv.z;
            Bs[ak + 3][ar] = bv.w;
        } else {
            const int bk = tid >> 4;         // 0..15
            const int bn = (tid & 15) * 4;   // 0..60
            const int gn = nBase + bn;
            float4 bv = *(const float4*)&B[(size_t)(kb + bk) * N + gn];
            if (B2) {
                float4 b2 = *(const float4*)&B2[(size_t)(kb + bk) * N + gn];
                bv.x += b2.x; bv.y += b2.y; bv.z += b2.z; bv.w += b2.w;
            }
            *(float4*)&Bs[bk][bn] = bv;
        }
        __syncthreads();

        #pragma unroll
        for (int k = 0; k < KT; ++k) {
            float4 a = *(const float4*)&As[k][ty * 4];
            float4 b = *(const float4*)&Bs[k][tx * 4];
            float av[4] = {a.x, a.y, a.z, a.w};
            float bv[4] = {b.x, b.y, b.z, b.w};
            #pragma unroll
            for (int i = 0; i < 4; ++i)
                #pragma unroll
                for (int j = 0; j < 4; ++j)
                    acc[i][j] = fmaf(av[i], bv[j], acc[i][j]);
        }
        __syncthreads();
    }

    #pragma unroll
    for (int i = 0; i < 4; ++i) {
        const int m = mBase + ty * 4 + i;
        if (m >= M) continue;
        #pragma unroll
        for (int j = 0; j < 4; ++j) {
            const int n = nBase + tx * 4 + j;
            if (n >= N) continue;
            if (storeT) C[(size_t)n * M + m] = acc[i][j];
            else        C[(size_t)m * N + n] = acc[i][j];
        }
    }
}

// ---------------- depthwise causal conv1d + SiLU (both branches) ----------------
__global__ __launch_bounds__(256)
void conv_silu_k(const float* __restrict__ xa, const float* __restrict__ x1p,
                 const float* __restrict__ w0, const float* __restrict__ b0,
                 const float* __restrict__ w1, const float* __restrict__ b1,
                 float* __restrict__ co0, float* __restrict__ co1)
{
    const int idx = blockIdx.x * blockDim.x + threadIdx.x; // 0 .. 2*2^21
    const int br  = idx >> 21;
    const int rem = idx & ((1 << 21) - 1);
    const int d = rem >> 10;
    const int l = rem & (LSEQ - 1);

    const float* xin = br ? x1p : xa;
    const float* w   = br ? w1 : w0;
    const float* bb  = br ? b1 : b0;
    float* out       = br ? co1 : co0;

    const float* row = xin + (size_t)d * LSEQ;
    float acc = bb[d];
    #pragma unroll
    for (int j = 0; j < D_CONV; ++j) {
        const int li = l - (D_CONV - 1) + j;
        const float xv = (li >= 0) ? row[li] : 0.f;
        acc = fmaf(w[d * D_CONV + j], xv, acc);
    }
    // silu
    out[rem] = acc / (1.f + expf(-acc));
}

// ---------------- selective scan ----------------
// one block = 16 channels (d) x 16 states (n); h kept per-thread
__global__ __launch_bounds__(256)
void scan_k(const float* __restrict__ delta,  // (D_INNER, L)
            const float* __restrict__ u,      // co (D_INNER, L)
            const float* __restrict__ xdbl,   // (96, L); B rows 64..79, C rows 80..95
            const float* __restrict__ A_log,  // (D_INNER, 16)
            const float* __restrict__ Dskip,  // (D_INNER)
            const float* __restrict__ z,      // (D_INNER, L)
            float* __restrict__ res)          // (D_INNER, L)
{
    const int tid = threadIdx.x;
    const int n  = tid & 15;
    const int dl = tid >> 4;
    const int d  = blockIdx.x * 16 + dl;

    const float Adn = -expf(A_log[d * D_STATE + n]);
    const float Dd  = Dskip[d];

    const float* drow = delta + (size_t)d * LSEQ;
    const float* urow = u     + (size_t)d * LSEQ;
    const float* zrow = z     + (size_t)d * LSEQ;
    const float* Brow = xdbl + (size_t)(DT_RANK + n) * LSEQ;
    const float* Crow = xdbl + (size_t)(DT_RANK + D_STATE + n) * LSEQ;
    float* orow = res + (size_t)d * LSEQ;

    float h = 0.f;
    for (int t = 0; t < LSEQ; ++t) {
        const float dv = drow[t];
        const float sp = (dv > 20.f) ? dv : log1pf(expf(dv));
        const float uv = urow[t];
        const float bt = Brow[t];
        const float ct = Crow[t];
        const float dA = expf(sp * Adn);
        h = fmaf(dA, h, sp * uv * bt);
        float y = h * ct;
        y += __shfl_xor(y, 1);
        y += __shfl_xor(y, 2);
        y += __shfl_xor(y, 4);
        y += __shfl_xor(y, 8);
        if (n == 0) {
            const float zv = zrow[t];
            const float sz = zv / (1.f + expf(-zv));
            orow[t] = (y + Dd * uv) * sz;
        }
    }
}

// ---------------- launcher ----------------
extern "C" void kernel_launch(void* const* d_in, const int* in_sizes, int n_in,
                              void* d_out, int out_size, void* d_ws, size_t ws_size,
                              hipStream_t stream)
{
    const float* x          = (const float*)d_in[0];
    const float* x1         = (const float*)d_in[1];
    const float* in_proj_w  = (const float*)d_in[2];
    const float* in_proj1_w = (const float*)d_in[3];
    const float* conv_w     = (const float*)d_in[4];
    const float* conv_b     = (const float*)d_in[5];
    const float* conv1_w    = (const float*)d_in[6];
    const float* conv1_b    = (const float*)d_in[7];
    const float* x_proj_w   = (const float*)d_in[8];
    const float* x_proj1_w  = (const float*)d_in[9];
    const float* dt_proj_w  = (const float*)d_in[10];
    const float* dt_proj1_w = (const float*)d_in[11];
    const float* A_log      = (const float*)d_in[12];
    const float* A_log1     = (const float*)d_in[13];
    const float* Dskip      = (const float*)d_in[14];
    const float* Dskip1     = (const float*)d_in[15];
    const float* out_proj_w = (const float*)d_in[16];

    float* ws = (float*)d_ws;
    const size_t CH = (size_t)D_INNER * LSEQ; // 2048*1024 = 2M floats

    // workspace layout (float offsets), with safe aliases:
    //   XZ     @ 0        (2*CH)  : xa = [0,CH), z = [CH,2CH)
    //   DELTA0 @ 0        (CH)    : aliases xa (dead after conv)
    //   X1P    @ 2CH      (CH)
    //   RES0   @ 2CH      (CH)    : aliases x1p (dead after conv)
    //   CO0    @ 3CH      (CH)
    //   CO1    @ 4CH      (CH)
    //   XDBL0  @ 5CH      (96K)
    //   XDBL1  @ 5CH+96K  (96K)
    //   DELTA1 @ 5CH+192K (CH)
    //   RES1   @ 6CH+192K (CH)
    float* XZ     = ws;
    float* XA     = XZ;
    float* Zg     = XZ + CH;
    float* DELTA0 = XZ;                       // alias
    float* X1P    = ws + 2 * CH;
    float* RES0   = X1P;                      // alias
    float* CO0    = ws + 3 * CH;
    float* CO1    = ws + 4 * CH;
    float* XDBL0  = ws + 5 * CH;
    float* XDBL1  = XDBL0 + (size_t)96 * LSEQ;
    float* DELTA1 = XDBL1 + (size_t)96 * LSEQ;
    float* RES1   = DELTA1 + CH;

    float* out = (float*)d_out;

    // 1) in_proj: xz[e,l] (M=4096) and in_proj1: x1p[e,l] (M=2048); NT
    {
        dim3 g(LSEQ / TS, (2 * D_INNER) / TS);
        hipLaunchKernelGGL(sgemm_k<true>, g, dim3(256), 0, stream,
                           in_proj_w, x, nullptr, XZ, 2 * D_INNER, LSEQ, D_MODEL, 0);
        dim3 g1(LSEQ / TS, D_INNER / TS);
        hipLaunchKernelGGL(sgemm_k<true>, g1, dim3(256), 0, stream,
                           in_proj1_w, x1, nullptr, X1P, D_INNER, LSEQ, D_MODEL, 0);
    }

    // 2) causal conv + silu, both branches
    {
        const int total = 2 * D_INNER * LSEQ;
        hipLaunchKernelGGL(conv_silu_k, dim3(total / 256), dim3(256), 0, stream,
                           XA, X1P, conv_w, conv_b, conv1_w, conv1_b, CO0, CO1);
    }

    // 3) x_proj: x_dbl[k,l] = x_proj_w (96,2048) @ co (2048,1024); NN
    {
        dim3 g(LSEQ / TS, (96 + TS - 1) / TS);
        hipLaunchKernelGGL(sgemm_k<false>, g, dim3(256), 0, stream,
                           x_proj_w, CO0, nullptr, XDBL0, 96, LSEQ, D_INNER, 0);
        hipLaunchKernelGGL(sgemm_k<false>, g, dim3(256), 0, stream,
                           x_proj1_w, CO1, nullptr, XDBL1, 96, LSEQ, D_INNER, 0);
    }

    // 4) dt_proj: delta[e,l] = dt_proj_w (2048,64) @ x_dbl[:64] (64,1024); NN
    {
        dim3 g(LSEQ / TS, D_INNER / TS);
        hipLaunchKernelGGL(sgemm_k<false>, g, dim3(256), 0, stream,
                           dt_proj_w, XDBL0, nullptr, DELTA0, D_INNER, LSEQ, DT_RANK, 0);
        hipLaunchKernelGGL(sgemm_k<false>, g, dim3(256), 0, stream,
                           dt_proj1_w, XDBL1, nullptr, DELTA1, D_INNER, LSEQ, DT_RANK, 0);
    }

    // 5) selective scan, both branches
    {
        dim3 g(D_INNER / 16);
        hipLaunchKernelGGL(scan_k, g, dim3(256), 0, stream,
                           DELTA0, CO0, XDBL0, A_log, Dskip, Zg, RES0);
        hipLaunchKernelGGL(scan_k, g, dim3(256), 0, stream,
                           DELTA1, CO1, XDBL1, A_log1, Dskip1, Zg, RES1);
    }

    // 6) out_proj: out[l,e] = sum_d (res0+res1)[d,l] * W[e,d]; NN, transposed store
    {
        dim3 g(LSEQ / TS, D_MODEL / TS);
        hipLaunchKernelGGL(sgemm_k<false>, g, dim3(256), 0, stream,
                           out_proj_w, RES0, RES1, out, D_MODEL, LSEQ, D_INNER, 1);
    }
}

// Round 2
// 1078.102 us; speedup vs baseline: 2.1509x; 2.1509x over previous
//
#include <hip/hip_runtime.h>
#include <hip/hip_bf16.h>
#include <math.h>

// ---------------- problem constants ----------------
#define D_MODEL 1024
#define D_STATE 16
#define D_CONV  4
#define D_INNER 2048
#define DT_RANK 64
#define LSEQ    1024

// ---------------- tiled fp32 GEMM ----------------
// C[m,n] = sum_k A[m*K+k] * B(k,n)
//   BNT=true : B is (N,K) row-major  -> B[n*K+k]   (dot of rows)
//   BNT=false: B is (K,N) row-major  -> B[k*N+n]   (optionally + B2)
// storeT=0: C[m*N+n]; storeT=1: C[n*M+m]
constexpr int TS = 64;
constexpr int KT = 16;

template<bool BNT>
__global__ __launch_bounds__(256)
void sgemm_k(const float* __restrict__ A, const float* __restrict__ B,
             const float* __restrict__ B2, float* __restrict__ C,
             int M, int N, int K, int storeT)
{
    __shared__ float As[KT][TS];
    __shared__ float Bs[KT][TS];
    const int tid = threadIdx.x;
    const int tx = tid & 15, ty = tid >> 4;
    const int mBase = blockIdx.y * TS;
    const int nBase = blockIdx.x * TS;

    float acc[4][4] = {};

    const int ar = tid >> 2;        // 0..63 row within tile
    const int ak = (tid & 3) * 4;   // 0,4,8,12

    for (int kb = 0; kb < K; kb += KT) {
        // ---- stage A (M,K) row-major, transposed into As[k][m]
        {
            const int gm = mBase + ar;
            float4 av = make_float4(0.f, 0.f, 0.f, 0.f);
            if (gm < M) av = *(const float4*)&A[(size_t)gm * K + kb + ak];
            As[ak + 0][ar] = av.x;
            As[ak + 1][ar] = av.y;
            As[ak + 2][ar] = av.z;
            As[ak + 3][ar] = av.w;
        }
        // ---- stage B
        if (BNT) {
            const int gn = nBase + ar;
            float4 bv = make_float4(0.f, 0.f, 0.f, 0.f);
            if (gn < N) bv = *(const float4*)&B[(size_t)gn * K + kb + ak];
            Bs[ak + 0][ar] = bv.x;
            Bs[ak + 1][ar] = bv.y;
            Bs[ak + 2][ar] = bv.z;
            Bs[ak + 3][ar] = bv.w;
        } else {
            const int bk = tid >> 4;         // 0..15
            const int bn = (tid & 15) * 4;   // 0..60
            const int gn = nBase + bn;
            float4 bv = *(const float4*)&B[(size_t)(kb + bk) * N + gn];
            if (B2) {
                float4 b2 = *(const float4*)&B2[(size_t)(kb + bk) * N + gn];
                bv.x += b2.x; bv.y += b2.y; bv.z += b2.z; bv.w += b2.w;
            }
            *(float4*)&Bs[bk][bn] = bv;
        }
        __syncthreads();

        #pragma unroll
        for (int k = 0; k < KT; ++k) {
            float4 a = *(const float4*)&As[k][ty * 4];
            float4 b = *(const float4*)&Bs[k][tx * 4];
            float av[4] = {a.x, a.y, a.z, a.w};
            float bv[4] = {b.x, b.y, b.z, b.w};
            #pragma unroll
            for (int i = 0; i < 4; ++i)
                #pragma unroll
                for (int j = 0; j < 4; ++j)
                    acc[i][j] = fmaf(av[i], bv[j], acc[i][j]);
        }
        __syncthreads();
    }

    #pragma unroll
    for (int i = 0; i < 4; ++i) {
        const int m = mBase + ty * 4 + i;
        if (m >= M) continue;
        #pragma unroll
        for (int j = 0; j < 4; ++j) {
            const int n = nBase + tx * 4 + j;
            if (n >= N) continue;
            if (storeT) C[(size_t)n * M + m] = acc[i][j];
            else        C[(size_t)m * N + n] = acc[i][j];
        }
    }
}

// ---------------- depthwise causal conv1d + SiLU (both branches) ----------------
__global__ __launch_bounds__(256)
void conv_silu_k(const float* __restrict__ xa, const float* __restrict__ x1p,
                 const float* __restrict__ w0, const float* __restrict__ b0,
                 const float* __restrict__ w1, const float* __restrict__ b1,
                 float* __restrict__ co0, float* __restrict__ co1)
{
    const int idx = blockIdx.x * blockDim.x + threadIdx.x; // 0 .. 2*2^21
    const int br  = idx >> 21;
    const int rem = idx & ((1 << 21) - 1);
    const int d = rem >> 10;
    const int l = rem & (LSEQ - 1);

    const float* xin = br ? x1p : xa;
    const float* w   = br ? w1 : w0;
    const float* bb  = br ? b1 : b0;
    float* out       = br ? co1 : co0;

    const float* row = xin + (size_t)d * LSEQ;
    float acc = bb[d];
    #pragma unroll
    for (int j = 0; j < D_CONV; ++j) {
        const int li = l - (D_CONV - 1) + j;
        const float xv = (li >= 0) ? row[li] : 0.f;
        acc = fmaf(w[d * D_CONV + j], xv, acc);
    }
    // silu
    out[rem] = acc / (1.f + expf(-acc));
}

// ---------------- chunk-parallel selective scan ----------------
// grid (D_INNER, 2): blockIdx.x = channel d, blockIdx.y = branch.
// 256 threads = 16 chunks (c = tid>>4) x 16 states (n = tid&15).
// Linear recurrence h_t = dA_t*h + dBu_t  ->  per-chunk (a = prod dA, b = chunk(0)),
// tiny serial scan over 16 chunks for h_start, then re-run chunk emitting y.
__global__ __launch_bounds__(256)
void scan2_k(const float* __restrict__ delta0, const float* __restrict__ u0,
             const float* __restrict__ xdbl0,  const float* __restrict__ Alog0,
             const float* __restrict__ Dsk0,
             const float* __restrict__ delta1, const float* __restrict__ u1,
             const float* __restrict__ xdbl1,  const float* __restrict__ Alog1,
             const float* __restrict__ Dsk1,
             const float* __restrict__ z,
             float* __restrict__ res0, float* __restrict__ res1)
{
    const int d   = blockIdx.x;
    const int br  = blockIdx.y;
    const int tid = threadIdx.x;
    const int n   = tid & 15;
    const int c   = tid >> 4;

    const float* delta = br ? delta1 : delta0;
    const float* u     = br ? u1     : u0;
    const float* xdbl  = br ? xdbl1  : xdbl0;
    const float* Alog  = br ? Alog1  : Alog0;
    const float* Dsk   = br ? Dsk1   : Dsk0;
    float* res         = br ? res1   : res0;

    const float Adn = -expf(Alog[d * D_STATE + n]);
    const float Dd  = Dsk[d];

    const float* drow = delta + (size_t)d * LSEQ;
    const float* urow = u     + (size_t)d * LSEQ;
    const float* zrow = z     + (size_t)d * LSEQ;
    const float* Brow = xdbl + (size_t)(DT_RANK + n) * LSEQ;
    const float* Crow = xdbl + (size_t)(DT_RANK + D_STATE + n) * LSEQ;
    float* orow = res + (size_t)d * LSEQ;

    const int t0 = c * 64;

    // ---- phase 1: chunk-local (a, b)
    float a = 1.f, b = 0.f;
    for (int tt = 0; tt < 64; tt += 4) {
        const float4 dv4 = *(const float4*)&drow[t0 + tt];
        const float4 uv4 = *(const float4*)&urow[t0 + tt];
        const float4 bv4 = *(const float4*)&Brow[t0 + tt];
        const float dvs[4] = {dv4.x, dv4.y, dv4.z, dv4.w};
        const float uvs[4] = {uv4.x, uv4.y, uv4.z, uv4.w};
        const float bvs[4] = {bv4.x, bv4.y, bv4.z, bv4.w};
        #pragma unroll
        for (int j = 0; j < 4; ++j) {
            const float dv = dvs[j];
            const float sp = (dv > 20.f) ? dv : log1pf(expf(dv));
            const float dA = expf(sp * Adn);
            a *= dA;
            b = fmaf(dA, b, sp * uvs[j] * bvs[j]);
        }
    }

    __shared__ float sA[16][16];   // [c][n]
    __shared__ float sB[16][16];
    __shared__ float sH[16][16];   // h_start per [c][n]
    sA[c][n] = a;
    sB[c][n] = b;
    __syncthreads();

    // ---- phase 2: serial scan over chunks (16 threads, one per n)
    if (tid < 16) {
        float hb = 0.f;
        #pragma unroll
        for (int cc = 0; cc < 16; ++cc) {
            sH[cc][tid] = hb;
            hb = fmaf(sA[cc][tid], hb, sB[cc][tid]);
        }
    }
    __syncthreads();

    // ---- phase 3: re-run chunk from h_start, emit y
    float h = sH[c][n];
    for (int tt = 0; tt < 64; tt += 4) {
        const float4 dv4 = *(const float4*)&drow[t0 + tt];
        const float4 uv4 = *(const float4*)&urow[t0 + tt];
        const float4 bv4 = *(const float4*)&Brow[t0 + tt];
        const float4 cv4 = *(const float4*)&Crow[t0 + tt];
        const float4 zv4 = *(const float4*)&zrow[t0 + tt];
        const float dvs[4] = {dv4.x, dv4.y, dv4.z, dv4.w};
        const float uvs[4] = {uv4.x, uv4.y, uv4.z, uv4.w};
        const float bvs[4] = {bv4.x, bv4.y, bv4.z, bv4.w};
        const float cvs[4] = {cv4.x, cv4.y, cv4.z, cv4.w};
        const float zvs[4] = {zv4.x, zv4.y, zv4.z, zv4.w};
        float y4[4];
        #pragma unroll
        for (int j = 0; j < 4; ++j) {
            const float dv = dvs[j];
            const float sp = (dv > 20.f) ? dv : log1pf(expf(dv));
            const float dA = expf(sp * Adn);
            h = fmaf(dA, h, sp * uvs[j] * bvs[j]);
            float y = h * cvs[j];
            y += __shfl_xor(y, 1);
            y += __shfl_xor(y, 2);
            y += __shfl_xor(y, 4);
            y += __shfl_xor(y, 8);
            y4[j] = y;
        }
        if (n == 0) {
            float4 o;
            float* op = (float*)&o;
            #pragma unroll
            for (int j = 0; j < 4; ++j) {
                const float zv = zvs[j];
                const float sz = zv / (1.f + expf(-zv));
                op[j] = (y4[j] + Dd * uvs[j]) * sz;
            }
            *(float4*)&orow[t0 + tt] = o;
        }
    }
}

// ---------------- launcher ----------------
extern "C" void kernel_launch(void* const* d_in, const int* in_sizes, int n_in,
                              void* d_out, int out_size, void* d_ws, size_t ws_size,
                              hipStream_t stream)
{
    const float* x          = (const float*)d_in[0];
    const float* x1         = (const float*)d_in[1];
    const float* in_proj_w  = (const float*)d_in[2];
    const float* in_proj1_w = (const float*)d_in[3];
    const float* conv_w     = (const float*)d_in[4];
    const float* conv_b     = (const float*)d_in[5];
    const float* conv1_w    = (const float*)d_in[6];
    const float* conv1_b    = (const float*)d_in[7];
    const float* x_proj_w   = (const float*)d_in[8];
    const float* x_proj1_w  = (const float*)d_in[9];
    const float* dt_proj_w  = (const float*)d_in[10];
    const float* dt_proj1_w = (const float*)d_in[11];
    const float* A_log      = (const float*)d_in[12];
    const float* A_log1     = (const float*)d_in[13];
    const float* Dskip      = (const float*)d_in[14];
    const float* Dskip1     = (const float*)d_in[15];
    const float* out_proj_w = (const float*)d_in[16];

    float* ws = (float*)d_ws;
    const size_t CH = (size_t)D_INNER * LSEQ; // 2048*1024 = 2M floats

    // workspace layout (float offsets), with safe aliases:
    //   XZ     @ 0        (2*CH)  : xa = [0,CH), z = [CH,2CH)
    //   DELTA0 @ 0        (CH)    : aliases xa (dead after conv)
    //   X1P    @ 2CH      (CH)
    //   RES0   @ 2CH      (CH)    : aliases x1p (dead after conv)
    //   CO0    @ 3CH      (CH)
    //   CO1    @ 4CH      (CH)
    //   XDBL0  @ 5CH      (96K)
    //   XDBL1  @ 5CH+96K  (96K)
    //   DELTA1 @ 5CH+192K (CH)
    //   RES1   @ 6CH+192K (CH)
    float* XZ     = ws;
    float* XA     = XZ;
    float* Zg     = XZ + CH;
    float* DELTA0 = XZ;                       // alias
    float* X1P    = ws + 2 * CH;
    float* RES0   = X1P;                      // alias
    float* CO0    = ws + 3 * CH;
    float* CO1    = ws + 4 * CH;
    float* XDBL0  = ws + 5 * CH;
    float* XDBL1  = XDBL0 + (size_t)96 * LSEQ;
    float* DELTA1 = XDBL1 + (size_t)96 * LSEQ;
    float* RES1   = DELTA1 + CH;

    float* out = (float*)d_out;

    // 1) in_proj: xz[e,l] (M=4096) and in_proj1: x1p[e,l] (M=2048); NT
    {
        dim3 g(LSEQ / TS, (2 * D_INNER) / TS);
        hipLaunchKernelGGL(sgemm_k<true>, g, dim3(256), 0, stream,
                           in_proj_w, x, nullptr, XZ, 2 * D_INNER, LSEQ, D_MODEL, 0);
        dim3 g1(LSEQ / TS, D_INNER / TS);
        hipLaunchKernelGGL(sgemm_k<true>, g1, dim3(256), 0, stream,
                           in_proj1_w, x1, nullptr, X1P, D_INNER, LSEQ, D_MODEL, 0);
    }

    // 2) causal conv + silu, both branches
    {
        const int total = 2 * D_INNER * LSEQ;
        hipLaunchKernelGGL(conv_silu_k, dim3(total / 256), dim3(256), 0, stream,
                           XA, X1P, conv_w, conv_b, conv1_w, conv1_b, CO0, CO1);
    }

    // 3) x_proj: x_dbl[k,l] = x_proj_w (96,2048) @ co (2048,1024); NN
    {
        dim3 g(LSEQ / TS, (96 + TS - 1) / TS);
        hipLaunchKernelGGL(sgemm_k<false>, g, dim3(256), 0, stream,
                           x_proj_w, CO0, nullptr, XDBL0, 96, LSEQ, D_INNER, 0);
        hipLaunchKernelGGL(sgemm_k<false>, g, dim3(256), 0, stream,
                           x_proj1_w, CO1, nullptr, XDBL1, 96, LSEQ, D_INNER, 0);
    }

    // 4) dt_proj: delta[e,l] = dt_proj_w (2048,64) @ x_dbl[:64] (64,1024); NN
    {
        dim3 g(LSEQ / TS, D_INNER / TS);
        hipLaunchKernelGGL(sgemm_k<false>, g, dim3(256), 0, stream,
                           dt_proj_w, XDBL0, nullptr, DELTA0, D_INNER, LSEQ, DT_RANK, 0);
        hipLaunchKernelGGL(sgemm_k<false>, g, dim3(256), 0, stream,
                           dt_proj1_w, XDBL1, nullptr, DELTA1, D_INNER, LSEQ, DT_RANK, 0);
    }

    // 5) chunk-parallel selective scan, both branches in one launch
    {
        dim3 g(D_INNER, 2);
        hipLaunchKernelGGL(scan2_k, g, dim3(256), 0, stream,
                           DELTA0, CO0, XDBL0, A_log, Dskip,
                           DELTA1, CO1, XDBL1, A_log1, Dskip1,
                           Zg, RES0, RES1);
    }

    // 6) out_proj: out[l,e] = sum_d (res0+res1)[d,l] * W[e,d]; NN, transposed store
    {
        dim3 g(LSEQ / TS, D_MODEL / TS);
        hipLaunchKernelGGL(sgemm_k<false>, g, dim3(256), 0, stream,
                           out_proj_w, RES0, RES1, out, D_MODEL, LSEQ, D_INNER, 1);
    }
}

// Round 3
// 801.731 us; speedup vs baseline: 2.8924x; 1.3447x over previous
//
#include <hip/hip_runtime.h>
#include <hip/hip_bf16.h>
#include <math.h>

// ---------------- problem constants ----------------
#define D_MODEL 1024
#define D_STATE 16
#define D_CONV  4
#define D_INNER 2048
#define DT_RANK 64
#define LSEQ    1024

// fast device math: native v_exp_f32 / v_log_f32 (~1 ulp, vs libm's ~100-inst paths)
__device__ __forceinline__ float softplus_f(float x) {
    // stable: exp underflows for x<-87 -> log(1)=0 (correct); for x>20 pass through
    const float sp = __logf(1.f + __expf(x));
    return (x > 20.f) ? x : sp;
}
__device__ __forceinline__ float silu_f(float x) {
    return x / (1.f + __expf(-x));
}

// ---------------- tiled fp32 GEMM ----------------
// C[m,n] = sum_k A[m*K+k] * B(k,n)
//   BNT=true : B is (N,K) row-major  -> B[n*K+k]   (dot of rows)
//   BNT=false: B is (K,N) row-major  -> B[k*N+n]   (optionally + B2)
// storeT=0: C[m*N+n]; storeT=1: C[n*M+m]
constexpr int TS = 64;
constexpr int KT = 16;
constexpr int LP = 4;   // LDS pad (floats): stride 68 -> store conflicts 4-way -> 2-way (free)

template<bool BNT>
__global__ __launch_bounds__(256)
void sgemm_k(const float* __restrict__ A, const float* __restrict__ B,
             const float* __restrict__ B2, float* __restrict__ C,
             int M, int N, int K, int storeT)
{
    __shared__ float As[KT][TS + LP];
    __shared__ float Bs[KT][TS + LP];
    const int tid = threadIdx.x;
    const int tx = tid & 15, ty = tid >> 4;
    const int mBase = blockIdx.y * TS;
    const int nBase = blockIdx.x * TS;

    float acc[4][4] = {};

    const int ar = tid >> 2;        // 0..63 row within tile
    const int ak = (tid & 3) * 4;   // 0,4,8,12

    for (int kb = 0; kb < K; kb += KT) {
        // ---- stage A (M,K) row-major, transposed into As[k][m]
        {
            const int gm = mBase + ar;
            float4 av = make_float4(0.f, 0.f, 0.f, 0.f);
            if (gm < M) av = *(const float4*)&A[(size_t)gm * K + kb + ak];
            As[ak + 0][ar] = av.x;
            As[ak + 1][ar] = av.y;
            As[ak + 2][ar] = av.z;
            As[ak + 3][ar] = av.w;
        }
        // ---- stage B
        if (BNT) {
            const int gn = nBase + ar;
            float4 bv = make_float4(0.f, 0.f, 0.f, 0.f);
            if (gn < N) bv = *(const float4*)&B[(size_t)gn * K + kb + ak];
            Bs[ak + 0][ar] = bv.x;
            Bs[ak + 1][ar] = bv.y;
            Bs[ak + 2][ar] = bv.z;
            Bs[ak + 3][ar] = bv.w;
        } else {
            const int bk = tid >> 4;         // 0..15
            const int bn = (tid & 15) * 4;   // 0..60
            const int gn = nBase + bn;
            float4 bv = *(const float4*)&B[(size_t)(kb + bk) * N + gn];
            if (B2) {
                float4 b2 = *(const float4*)&B2[(size_t)(kb + bk) * N + gn];
                bv.x += b2.x; bv.y += b2.y; bv.z += b2.z; bv.w += b2.w;
            }
            *(float4*)&Bs[bk][bn] = bv;
        }
        __syncthreads();

        #pragma unroll
        for (int k = 0; k < KT; ++k) {
            float4 a = *(const float4*)&As[k][ty * 4];
            float4 b = *(const float4*)&Bs[k][tx * 4];
            float av[4] = {a.x, a.y, a.z, a.w};
            float bv[4] = {b.x, b.y, b.z, b.w};
            #pragma unroll
            for (int i = 0; i < 4; ++i)
                #pragma unroll
                for (int j = 0; j < 4; ++j)
                    acc[i][j] = fmaf(av[i], bv[j], acc[i][j]);
        }
        __syncthreads();
    }

    #pragma unroll
    for (int i = 0; i < 4; ++i) {
        const int m = mBase + ty * 4 + i;
        if (m >= M) continue;
        #pragma unroll
        for (int j = 0; j < 4; ++j) {
            const int n = nBase + tx * 4 + j;
            if (n >= N) continue;
            if (storeT) C[(size_t)n * M + m] = acc[i][j];
            else        C[(size_t)m * N + n] = acc[i][j];
        }
    }
}

// ---------------- depthwise causal conv1d + SiLU (both branches) ----------------
__global__ __launch_bounds__(256)
void conv_silu_k(const float* __restrict__ xa, const float* __restrict__ x1p,
                 const float* __restrict__ w0, const float* __restrict__ b0,
                 const float* __restrict__ w1, const float* __restrict__ b1,
                 float* __restrict__ co0, float* __restrict__ co1)
{
    const int idx = blockIdx.x * blockDim.x + threadIdx.x; // 0 .. 2*2^21
    const int br  = idx >> 21;
    const int rem = idx & ((1 << 21) - 1);
    const int d = rem >> 10;
    const int l = rem & (LSEQ - 1);

    const float* xin = br ? x1p : xa;
    const float* w   = br ? w1 : w0;
    const float* bb  = br ? b1 : b0;
    float* out       = br ? co1 : co0;

    const float* row = xin + (size_t)d * LSEQ;
    float acc = bb[d];
    #pragma unroll
    for (int j = 0; j < D_CONV; ++j) {
        const int li = l - (D_CONV - 1) + j;
        const float xv = (li >= 0) ? row[li] : 0.f;
        acc = fmaf(w[d * D_CONV + j], xv, acc);
    }
    out[rem] = silu_f(acc);
}

// ---------------- chunk-parallel selective scan ----------------
// grid (D_INNER, 2): blockIdx.x = channel d, blockIdx.y = branch.
// 256 threads = 16 chunks (c = tid>>4) x 16 states (n = tid&15).
// Linear recurrence h_t = dA_t*h + dBu_t  ->  per-chunk (a = prod dA, b = chunk(0)),
// tiny serial scan over 16 chunks for h_start, then re-run chunk emitting y.
__global__ __launch_bounds__(256)
void scan2_k(const float* __restrict__ delta0, const float* __restrict__ u0,
             const float* __restrict__ xdbl0,  const float* __restrict__ Alog0,
             const float* __restrict__ Dsk0,
             const float* __restrict__ delta1, const float* __restrict__ u1,
             const float* __restrict__ xdbl1,  const float* __restrict__ Alog1,
             const float* __restrict__ Dsk1,
             const float* __restrict__ z,
             float* __restrict__ res0, float* __restrict__ res1)
{
    const int d   = blockIdx.x;
    const int br  = blockIdx.y;
    const int tid = threadIdx.x;
    const int n   = tid & 15;
    const int c   = tid >> 4;

    const float* delta = br ? delta1 : delta0;
    const float* u     = br ? u1     : u0;
    const float* xdbl  = br ? xdbl1  : xdbl0;
    const float* Alog  = br ? Alog1  : Alog0;
    const float* Dsk   = br ? Dsk1   : Dsk0;
    float* res         = br ? res1   : res0;

    const float Adn = -__expf(Alog[d * D_STATE + n]);
    const float Dd  = Dsk[d];

    const float* drow = delta + (size_t)d * LSEQ;
    const float* urow = u     + (size_t)d * LSEQ;
    const float* zrow = z     + (size_t)d * LSEQ;
    const float* Brow = xdbl + (size_t)(DT_RANK + n) * LSEQ;
    const float* Crow = xdbl + (size_t)(DT_RANK + D_STATE + n) * LSEQ;
    float* orow = res + (size_t)d * LSEQ;

    const int t0 = c * 64;

    // ---- phase 1: chunk-local (a, b)
    float a = 1.f, b = 0.f;
    for (int tt = 0; tt < 64; tt += 4) {
        const float4 dv4 = *(const float4*)&drow[t0 + tt];
        const float4 uv4 = *(const float4*)&urow[t0 + tt];
        const float4 bv4 = *(const float4*)&Brow[t0 + tt];
        const float dvs[4] = {dv4.x, dv4.y, dv4.z, dv4.w};
        const float uvs[4] = {uv4.x, uv4.y, uv4.z, uv4.w};
        const float bvs[4] = {bv4.x, bv4.y, bv4.z, bv4.w};
        #pragma unroll
        for (int j = 0; j < 4; ++j) {
            const float sp = softplus_f(dvs[j]);
            const float dA = __expf(sp * Adn);
            a *= dA;
            b = fmaf(dA, b, sp * uvs[j] * bvs[j]);
        }
    }

    __shared__ float sA[16][16];   // [c][n]
    __shared__ float sB[16][16];
    __shared__ float sH[16][16];   // h_start per [c][n]
    sA[c][n] = a;
    sB[c][n] = b;
    __syncthreads();

    // ---- phase 2: serial scan over chunks (16 threads, one per n)
    if (tid < 16) {
        float hb = 0.f;
        #pragma unroll
        for (int cc = 0; cc < 16; ++cc) {
            sH[cc][tid] = hb;
            hb = fmaf(sA[cc][tid], hb, sB[cc][tid]);
        }
    }
    __syncthreads();

    // ---- phase 3: re-run chunk from h_start, emit y
    float h = sH[c][n];
    for (int tt = 0; tt < 64; tt += 4) {
        const float4 dv4 = *(const float4*)&drow[t0 + tt];
        const float4 uv4 = *(const float4*)&urow[t0 + tt];
        const float4 bv4 = *(const float4*)&Brow[t0 + tt];
        const float4 cv4 = *(const float4*)&Crow[t0 + tt];
        const float4 zv4 = *(const float4*)&zrow[t0 + tt];
        const float dvs[4] = {dv4.x, dv4.y, dv4.z, dv4.w};
        const float uvs[4] = {uv4.x, uv4.y, uv4.z, uv4.w};
        const float bvs[4] = {bv4.x, bv4.y, bv4.z, bv4.w};
        const float cvs[4] = {cv4.x, cv4.y, cv4.z, cv4.w};
        const float zvs[4] = {zv4.x, zv4.y, zv4.z, zv4.w};
        float y4[4];
        #pragma unroll
        for (int j = 0; j < 4; ++j) {
            const float sp = softplus_f(dvs[j]);
            const float dA = __expf(sp * Adn);
            h = fmaf(dA, h, sp * uvs[j] * bvs[j]);
            float y = h * cvs[j];
            y += __shfl_xor(y, 1);
            y += __shfl_xor(y, 2);
            y += __shfl_xor(y, 4);
            y += __shfl_xor(y, 8);
            y4[j] = y;
        }
        if (n == 0) {
            float4 o;
            float* op = (float*)&o;
            #pragma unroll
            for (int j = 0; j < 4; ++j) {
                op[j] = (y4[j] + Dd * uvs[j]) * silu_f(zvs[j]);
            }
            *(float4*)&orow[t0 + tt] = o;
        }
    }
}

// ---------------- launcher ----------------
extern "C" void kernel_launch(void* const* d_in, const int* in_sizes, int n_in,
                              void* d_out, int out_size, void* d_ws, size_t ws_size,
                              hipStream_t stream)
{
    const float* x          = (const float*)d_in[0];
    const float* x1         = (const float*)d_in[1];
    const float* in_proj_w  = (const float*)d_in[2];
    const float* in_proj1_w = (const float*)d_in[3];
    const float* conv_w     = (const float*)d_in[4];
    const float* conv_b     = (const float*)d_in[5];
    const float* conv1_w    = (const float*)d_in[6];
    const float* conv1_b    = (const float*)d_in[7];
    const float* x_proj_w   = (const float*)d_in[8];
    const float* x_proj1_w  = (const float*)d_in[9];
    const float* dt_proj_w  = (const float*)d_in[10];
    const float* dt_proj1_w = (const float*)d_in[11];
    const float* A_log      = (const float*)d_in[12];
    const float* A_log1     = (const float*)d_in[13];
    const float* Dskip      = (const float*)d_in[14];
    const float* Dskip1     = (const float*)d_in[15];
    const float* out_proj_w = (const float*)d_in[16];

    float* ws = (float*)d_ws;
    const size_t CH = (size_t)D_INNER * LSEQ; // 2048*1024 = 2M floats

    // workspace layout (float offsets), with safe aliases:
    //   XZ     @ 0        (2*CH)  : xa = [0,CH), z = [CH,2CH)
    //   DELTA0 @ 0        (CH)    : aliases xa (dead after conv)
    //   X1P    @ 2CH      (CH)
    //   RES0   @ 2CH      (CH)    : aliases x1p (dead after conv)
    //   CO0    @ 3CH      (CH)
    //   CO1    @ 4CH      (CH)
    //   XDBL0  @ 5CH      (96K)
    //   XDBL1  @ 5CH+96K  (96K)
    //   DELTA1 @ 5CH+192K (CH)
    //   RES1   @ 6CH+192K (CH)
    float* XZ     = ws;
    float* XA     = XZ;
    float* Zg     = XZ + CH;
    float* DELTA0 = XZ;                       // alias
    float* X1P    = ws + 2 * CH;
    float* RES0   = X1P;                      // alias
    float* CO0    = ws + 3 * CH;
    float* CO1    = ws + 4 * CH;
    float* XDBL0  = ws + 5 * CH;
    float* XDBL1  = XDBL0 + (size_t)96 * LSEQ;
    float* DELTA1 = XDBL1 + (size_t)96 * LSEQ;
    float* RES1   = DELTA1 + CH;

    float* out = (float*)d_out;

    // 1) in_proj: xz[e,l] (M=4096) and in_proj1: x1p[e,l] (M=2048); NT
    {
        dim3 g(LSEQ / TS, (2 * D_INNER) / TS);
        hipLaunchKernelGGL(sgemm_k<true>, g, dim3(256), 0, stream,
                           in_proj_w, x, nullptr, XZ, 2 * D_INNER, LSEQ, D_MODEL, 0);
        dim3 g1(LSEQ / TS, D_INNER / TS);
        hipLaunchKernelGGL(sgemm_k<true>, g1, dim3(256), 0, stream,
                           in_proj1_w, x1, nullptr, X1P, D_INNER, LSEQ, D_MODEL, 0);
    }

    // 2) causal conv + silu, both branches
    {
        const int total = 2 * D_INNER * LSEQ;
        hipLaunchKernelGGL(conv_silu_k, dim3(total / 256), dim3(256), 0, stream,
                           XA, X1P, conv_w, conv_b, conv1_w, conv1_b, CO0, CO1);
    }

    // 3) x_proj: x_dbl[k,l] = x_proj_w (96,2048) @ co (2048,1024); NN
    {
        dim3 g(LSEQ / TS, (96 + TS - 1) / TS);
        hipLaunchKernelGGL(sgemm_k<false>, g, dim3(256), 0, stream,
                           x_proj_w, CO0, nullptr, XDBL0, 96, LSEQ, D_INNER, 0);
        hipLaunchKernelGGL(sgemm_k<false>, g, dim3(256), 0, stream,
                           x_proj1_w, CO1, nullptr, XDBL1, 96, LSEQ, D_INNER, 0);
    }

    // 4) dt_proj: delta[e,l] = dt_proj_w (2048,64) @ x_dbl[:64] (64,1024); NN
    {
        dim3 g(LSEQ / TS, D_INNER / TS);
        hipLaunchKernelGGL(sgemm_k<false>, g, dim3(256), 0, stream,
                           dt_proj_w, XDBL0, nullptr, DELTA0, D_INNER, LSEQ, DT_RANK, 0);
        hipLaunchKernelGGL(sgemm_k<false>, g, dim3(256), 0, stream,
                           dt_proj1_w, XDBL1, nullptr, DELTA1, D_INNER, LSEQ, DT_RANK, 0);
    }

    // 5) chunk-parallel selective scan, both branches in one launch
    {
        dim3 g(D_INNER, 2);
        hipLaunchKernelGGL(scan2_k, g, dim3(256), 0, stream,
                           DELTA0, CO0, XDBL0, A_log, Dskip,
                           DELTA1, CO1, XDBL1, A_log1, Dskip1,
                           Zg, RES0, RES1);
    }

    // 6) out_proj: out[l,e] = sum_d (res0+res1)[d,l] * W[e,d]; NN, transposed store
    {
        dim3 g(LSEQ / TS, D_MODEL / TS);
        hipLaunchKernelGGL(sgemm_k<false>, g, dim3(256), 0, stream,
                           out_proj_w, RES0, RES1, out, D_MODEL, LSEQ, D_INNER, 1);
    }
}

// Round 4
// 571.765 us; speedup vs baseline: 4.0557x; 1.4022x over previous
//
#include <hip/hip_runtime.h>
#include <hip/hip_bf16.h>
#include <math.h>

// ---------------- problem constants ----------------
#define D_MODEL 1024
#define D_STATE 16
#define D_CONV  4
#define D_INNER 2048
#define DT_RANK 64
#define LSEQ    1024

typedef short bf16x8 __attribute__((ext_vector_type(8)));
typedef float f32x4  __attribute__((ext_vector_type(4)));

// fast device math: native v_exp_f32 / v_log_f32
__device__ __forceinline__ float softplus_f(float x) {
    const float sp = __logf(1.f + __expf(x));
    return (x > 20.f) ? x : sp;
}
__device__ __forceinline__ float silu_f(float x) {
    return x / (1.f + __expf(-x));
}
// fp32 -> bf16 round-to-nearest-even
__device__ __forceinline__ unsigned short f2bf(float f) {
    union { float f; unsigned int u; } c; c.f = f;
    const unsigned int u = c.u;
    return (unsigned short)((u + 0x7FFFu + ((u >> 16) & 1u)) >> 16);
}

// ---------------- elementwise fp32 -> bf16 convert ----------------
__global__ __launch_bounds__(256)
void cvt_k(const float* __restrict__ in, unsigned short* __restrict__ out, int n4)
{
    const int i = blockIdx.x * 256 + threadIdx.x;
    if (i >= n4) return;
    const float4 v = *(const float4*)&in[(size_t)i * 4];
    ushort4 o;
    o.x = f2bf(v.x); o.y = f2bf(v.y); o.z = f2bf(v.z); o.w = f2bf(v.w);
    *(ushort4*)&out[(size_t)i * 4] = o;
}

// ---------------- transpose + add + convert: REST[l][d] = bf16(res0[d][l]+res1[d][l]) ----
__global__ __launch_bounds__(256)
void cvtT_add_k(const float* __restrict__ r0, const float* __restrict__ r1,
                unsigned short* __restrict__ dst)
{
    __shared__ float s[32][33];
    const int tx = threadIdx.x & 31, ty = threadIdx.x >> 5;   // 32 x 8
    const int dBase = blockIdx.y * 32, lBase = blockIdx.x * 32;
    #pragma unroll
    for (int i = 0; i < 4; ++i) {
        const int d = dBase + ty + i * 8;
        const size_t off = (size_t)d * LSEQ + lBase + tx;
        s[ty + i * 8][tx] = r0[off] + r1[off];
    }
    __syncthreads();
    #pragma unroll
    for (int i = 0; i < 4; ++i) {
        const int l = lBase + ty + i * 8;
        dst[(size_t)l * D_INNER + dBase + tx] = f2bf(s[tx][ty + i * 8]);
    }
}

// ---------------- bf16 MFMA GEMM, NT layout ----------------
// C[m,n] = sum_k A[m*K+k] * B[n*K+k]; A (M,K) bf16, B (N,K) bf16, C (M,N) f32.
// 128x128 tile, 4 waves (2x2), each wave 64x64 = 4x4 frags of 16x16x32.
__global__ __launch_bounds__(256)
void mfma_nt_k(const unsigned short* __restrict__ A, const unsigned short* __restrict__ B,
               float* __restrict__ C, int M, int N, int K)
{
    __shared__ unsigned short As[128][40];   // +8 pad: 80B row stride -> ~2-way conflicts
    __shared__ unsigned short Bs[128][40];
    const int tid = threadIdx.x;
    const int mBase = blockIdx.y * 128, nBase = blockIdx.x * 128;
    const int lane = tid & 63, w = tid >> 6;
    const int wr = w >> 1, wc = w & 1;
    const int l15 = lane & 15, l4 = lane >> 4;

    f32x4 acc[4][4] = {};

    const int sr = tid >> 2;        // 0..63
    const int sk = (tid & 3) * 8;   // 0,8,16,24

    for (int kb = 0; kb < K; kb += 32) {
        #pragma unroll
        for (int it = 0; it < 2; ++it) {
            const int r = it * 64 + sr;
            const float4 va = *(const float4*)&A[(size_t)(mBase + r) * K + kb + sk];
            *(float4*)&As[r][sk] = va;
            const float4 vb = *(const float4*)&B[(size_t)(nBase + r) * K + kb + sk];
            *(float4*)&Bs[r][sk] = vb;
        }
        __syncthreads();
        bf16x8 af[4], bfr[4];
        #pragma unroll
        for (int i = 0; i < 4; ++i) {
            af[i]  = *(const bf16x8*)&As[wr * 64 + i * 16 + l15][l4 * 8];
            bfr[i] = *(const bf16x8*)&Bs[wc * 64 + i * 16 + l15][l4 * 8];
        }
        #pragma unroll
        for (int i = 0; i < 4; ++i)
            #pragma unroll
            for (int j = 0; j < 4; ++j)
                acc[i][j] = __builtin_amdgcn_mfma_f32_16x16x32_bf16(af[i], bfr[j], acc[i][j], 0, 0, 0);
        __syncthreads();
    }

    #pragma unroll
    for (int i = 0; i < 4; ++i) {
        const int row0 = mBase + wr * 64 + i * 16 + l4 * 4;
        #pragma unroll
        for (int j = 0; j < 4; ++j) {
            const int col = nBase + wc * 64 + j * 16 + l15;
            #pragma unroll
            for (int r = 0; r < 4; ++r)
                C[(size_t)(row0 + r) * N + col] = acc[i][j][r];
        }
    }
}

// ---------------- tiled fp32 GEMM (small GEMMs: x_proj, dt_proj) ----------------
constexpr int TS = 64;
constexpr int KT = 16;
constexpr int LP = 4;

template<bool BNT>
__global__ __launch_bounds__(256)
void sgemm_k(const float* __restrict__ A, const float* __restrict__ B,
             const float* __restrict__ B2, float* __restrict__ C,
             int M, int N, int K, int storeT)
{
    __shared__ float As[KT][TS + LP];
    __shared__ float Bs[KT][TS + LP];
    const int tid = threadIdx.x;
    const int tx = tid & 15, ty = tid >> 4;
    const int mBase = blockIdx.y * TS;
    const int nBase = blockIdx.x * TS;

    float acc[4][4] = {};

    const int ar = tid >> 2;
    const int ak = (tid & 3) * 4;

    for (int kb = 0; kb < K; kb += KT) {
        {
            const int gm = mBase + ar;
            float4 av = make_float4(0.f, 0.f, 0.f, 0.f);
            if (gm < M) av = *(const float4*)&A[(size_t)gm * K + kb + ak];
            As[ak + 0][ar] = av.x;
            As[ak + 1][ar] = av.y;
            As[ak + 2][ar] = av.z;
            As[ak + 3][ar] = av.w;
        }
        if (BNT) {
            const int gn = nBase + ar;
            float4 bv = make_float4(0.f, 0.f, 0.f, 0.f);
            if (gn < N) bv = *(const float4*)&B[(size_t)gn * K + kb + ak];
            Bs[ak + 0][ar] = bv.x;
            Bs[ak + 1][ar] = bv.y;
            Bs[ak + 2][ar] = bv.z;
            Bs[ak + 3][ar] = bv.w;
        } else {
            const int bk = tid >> 4;
            const int bn = (tid & 15) * 4;
            const int gn = nBase + bn;
            float4 bv = *(const float4*)&B[(size_t)(kb + bk) * N + gn];
            if (B2) {
                float4 b2 = *(const float4*)&B2[(size_t)(kb + bk) * N + gn];
                bv.x += b2.x; bv.y += b2.y; bv.z += b2.z; bv.w += b2.w;
            }
            *(float4*)&Bs[bk][bn] = bv;
        }
        __syncthreads();

        #pragma unroll
        for (int k = 0; k < KT; ++k) {
            float4 a = *(const float4*)&As[k][ty * 4];
            float4 b = *(const float4*)&Bs[k][tx * 4];
            float av[4] = {a.x, a.y, a.z, a.w};
            float bv[4] = {b.x, b.y, b.z, b.w};
            #pragma unroll
            for (int i = 0; i < 4; ++i)
                #pragma unroll
                for (int j = 0; j < 4; ++j)
                    acc[i][j] = fmaf(av[i], bv[j], acc[i][j]);
        }
        __syncthreads();
    }

    #pragma unroll
    for (int i = 0; i < 4; ++i) {
        const int m = mBase + ty * 4 + i;
        if (m >= M) continue;
        #pragma unroll
        for (int j = 0; j < 4; ++j) {
            const int n = nBase + tx * 4 + j;
            if (n >= N) continue;
            if (storeT) C[(size_t)n * M + m] = acc[i][j];
            else        C[(size_t)m * N + n] = acc[i][j];
        }
    }
}

// ---------------- depthwise causal conv1d + SiLU (both branches) ----------------
__global__ __launch_bounds__(256)
void conv_silu_k(const float* __restrict__ xa, const float* __restrict__ x1p,
                 const float* __restrict__ w0, const float* __restrict__ b0,
                 const float* __restrict__ w1, const float* __restrict__ b1,
                 float* __restrict__ co0, float* __restrict__ co1)
{
    const int idx = blockIdx.x * blockDim.x + threadIdx.x;
    const int br  = idx >> 21;
    const int rem = idx & ((1 << 21) - 1);
    const int d = rem >> 10;
    const int l = rem & (LSEQ - 1);

    const float* xin = br ? x1p : xa;
    const float* w   = br ? w1 : w0;
    const float* bb  = br ? b1 : b0;
    float* out       = br ? co1 : co0;

    const float* row = xin + (size_t)d * LSEQ;
    float acc = bb[d];
    #pragma unroll
    for (int j = 0; j < D_CONV; ++j) {
        const int li = l - (D_CONV - 1) + j;
        const float xv = (li >= 0) ? row[li] : 0.f;
        acc = fmaf(w[d * D_CONV + j], xv, acc);
    }
    out[rem] = silu_f(acc);
}

// ---------------- prep: softplus(delta) in place, silu(z) -> gz ----------------
__global__ __launch_bounds__(256)
void prep_k(float* sp0, float* sp1, const float* __restrict__ z, float* __restrict__ gz)
{
    const int Q = (D_INNER * LSEQ) / 4;  // float4 groups per CH
    const int i = blockIdx.x * 256 + threadIdx.x;
    if (i < Q) {
        float4 v = *(const float4*)&sp0[(size_t)i * 4];
        v.x = softplus_f(v.x); v.y = softplus_f(v.y); v.z = softplus_f(v.z); v.w = softplus_f(v.w);
        *(float4*)&sp0[(size_t)i * 4] = v;
    } else if (i < 2 * Q) {
        const int j = i - Q;
        float4 v = *(const float4*)&sp1[(size_t)j * 4];
        v.x = softplus_f(v.x); v.y = softplus_f(v.y); v.z = softplus_f(v.z); v.w = softplus_f(v.w);
        *(float4*)&sp1[(size_t)j * 4] = v;
    } else {
        const int j = i - 2 * Q;
        float4 v = *(const float4*)&z[(size_t)j * 4];
        v.x = silu_f(v.x); v.y = silu_f(v.y); v.z = silu_f(v.z); v.w = silu_f(v.w);
        *(float4*)&gz[(size_t)j * 4] = v;
    }
}

// ---------------- chunk-parallel selective scan (post-prep) ----------------
// NOTE: res aliases u (in-place) -> no __restrict__ on those.
__global__ __launch_bounds__(256)
void scan3_k(const float* sp0, const float* u0, const float* xd0,
             const float* Al0, const float* Dk0,
             const float* sp1, const float* u1, const float* xd1,
             const float* Al1, const float* Dk1,
             const float* gz, float* res0, float* res1)
{
    const int d   = blockIdx.x;
    const int br  = blockIdx.y;
    const int tid = threadIdx.x;
    const int n   = tid & 15;
    const int c   = tid >> 4;

    const float* sp = br ? sp1 : sp0;
    const float* u  = br ? u1  : u0;
    const float* xd = br ? xd1 : xd0;
    const float* Al = br ? Al1 : Al0;
    const float* Dk = br ? Dk1 : Dk0;
    float* res      = br ? res1 : res0;

    const float Adn = -__expf(Al[d * D_STATE + n]);
    const float Dd  = Dk[d];

    const float* srow = sp + (size_t)d * LSEQ;
    const float* urow = u  + (size_t)d * LSEQ;
    const float* grow = gz + (size_t)d * LSEQ;
    const float* Brow = xd + (size_t)(DT_RANK + n) * LSEQ;
    const float* Crow = xd + (size_t)(DT_RANK + D_STATE + n) * LSEQ;
    float* orow = res + (size_t)d * LSEQ;

    const int t0 = c * 64;

    // ---- phase 1: chunk-local (a, b)
    float a = 1.f, b = 0.f;
    for (int tt = 0; tt < 64; tt += 4) {
        const float4 s4 = *(const float4*)&srow[t0 + tt];
        const float4 u4 = *(const float4*)&urow[t0 + tt];
        const float4 b4 = *(const float4*)&Brow[t0 + tt];
        const float sps[4] = {s4.x, s4.y, s4.z, s4.w};
        const float uvs[4] = {u4.x, u4.y, u4.z, u4.w};
        const float bvs[4] = {b4.x, b4.y, b4.z, b4.w};
        #pragma unroll
        for (int j = 0; j < 4; ++j) {
            const float dA = __expf(sps[j] * Adn);
            a *= dA;
            b = fmaf(dA, b, sps[j] * uvs[j] * bvs[j]);
        }
    }

    __shared__ float sAm[16][16];
    __shared__ float sBm[16][16];
    __shared__ float sHm[16][16];
    sAm[c][n] = a;
    sBm[c][n] = b;
    __syncthreads();

    // ---- phase 2: serial scan over chunks
    if (tid < 16) {
        float hb = 0.f;
        #pragma unroll
        for (int cc = 0; cc < 16; ++cc) {
            sHm[cc][tid] = hb;
            hb = fmaf(sAm[cc][tid], hb, sBm[cc][tid]);
        }
    }
    __syncthreads();

    // ---- phase 3: re-run chunk from h_start, emit y
    float h = sHm[c][n];
    for (int tt = 0; tt < 64; tt += 4) {
        const float4 s4 = *(const float4*)&srow[t0 + tt];
        const float4 u4 = *(const float4*)&urow[t0 + tt];
        const float4 b4 = *(const float4*)&Brow[t0 + tt];
        const float4 c4 = *(const float4*)&Crow[t0 + tt];
        const float4 g4 = *(const float4*)&grow[t0 + tt];
        const float sps[4] = {s4.x, s4.y, s4.z, s4.w};
        const float uvs[4] = {u4.x, u4.y, u4.z, u4.w};
        const float bvs[4] = {b4.x, b4.y, b4.z, b4.w};
        const float cvs[4] = {c4.x, c4.y, c4.z, c4.w};
        const float gzs[4] = {g4.x, g4.y, g4.z, g4.w};
        float y4[4];
        #pragma unroll
        for (int j = 0; j < 4; ++j) {
            const float dA = __expf(sps[j] * Adn);
            h = fmaf(dA, h, sps[j] * uvs[j] * bvs[j]);
            float y = h * cvs[j];
            y += __shfl_xor(y, 1);
            y += __shfl_xor(y, 2);
            y += __shfl_xor(y, 4);
            y += __shfl_xor(y, 8);
            y4[j] = y;
        }
        if (n == 0) {
            float4 o;
            float* op = (float*)&o;
            #pragma unroll
            for (int j = 0; j < 4; ++j)
                op[j] = (y4[j] + Dd * uvs[j]) * gzs[j];
            *(float4*)&orow[t0 + tt] = o;
        }
    }
}

// ---------------- launcher ----------------
extern "C" void kernel_launch(void* const* d_in, const int* in_sizes, int n_in,
                              void* d_out, int out_size, void* d_ws, size_t ws_size,
                              hipStream_t stream)
{
    const float* x          = (const float*)d_in[0];
    const float* x1         = (const float*)d_in[1];
    const float* in_proj_w  = (const float*)d_in[2];
    const float* in_proj1_w = (const float*)d_in[3];
    const float* conv_w     = (const float*)d_in[4];
    const float* conv_b     = (const float*)d_in[5];
    const float* conv1_w    = (const float*)d_in[6];
    const float* conv1_b    = (const float*)d_in[7];
    const float* x_proj_w   = (const float*)d_in[8];
    const float* x_proj1_w  = (const float*)d_in[9];
    const float* dt_proj_w  = (const float*)d_in[10];
    const float* dt_proj1_w = (const float*)d_in[11];
    const float* A_log      = (const float*)d_in[12];
    const float* A_log1     = (const float*)d_in[13];
    const float* Dskip      = (const float*)d_in[14];
    const float* Dskip1     = (const float*)d_in[15];
    const float* out_proj_w = (const float*)d_in[16];

    float* ws = (float*)d_ws;
    const size_t CH = (size_t)D_INNER * LSEQ;        // 2 Mi f32
    const size_t XD = (size_t)96 * LSEQ;             // 96 Ki f32
    const size_t F  = 5 * CH + 2 * XD;               // scratch region base

    // layout (f32 units), total = 7*CH + 192K (same as known-good round 3):
    //   [0,CH)        xa  -> gz (after conv)
    //   [CH,2CH)      z
    //   [2CH,3CH)     x1p (dead after conv)
    //   [3CH,4CH)     co0 -> res0 (in place)
    //   [4CH,5CH)     co1 -> res1 (in place)
    //   [5CH,5CH+2XD) xdbl0, xdbl1
    //   [F,F+2CH)     time-sliced: {WB+XB} -> {WB1+X1B} -> {delta0,delta1=sp0,sp1} -> {OWB+RESTB}
    float* XA     = ws;
    float* GZ     = ws;                  // alias xa
    float* Zg     = ws + CH;
    float* X1P    = ws + 2 * CH;
    float* CO0    = ws + 3 * CH;
    float* CO1    = ws + 4 * CH;
    float* RES0   = CO0;                 // in-place
    float* RES1   = CO1;                 // in-place
    float* XDBL0  = ws + 5 * CH;
    float* XDBL1  = XDBL0 + XD;
    float* DELTA0 = ws + F;
    float* DELTA1 = ws + F + CH;
    float* XZ     = ws;                  // [0,2CH): xa+z written by in_proj

    unsigned short* WB    = (unsigned short*)(ws + F);            // 4096x1024 bf16 (spans CH f32)
    unsigned short* XB    = (unsigned short*)(ws + F + CH);       // 1024x1024 bf16
    unsigned short* WB1   = (unsigned short*)(ws + F);            // 2048x1024 bf16
    unsigned short* X1B   = (unsigned short*)(ws + F + CH / 2);   // 1024x1024 bf16
    unsigned short* OWB   = (unsigned short*)(ws + F);            // 1024x2048 bf16
    unsigned short* RESTB = (unsigned short*)(ws + F + CH / 2);   // 1024x2048 bf16

    float* out = (float*)d_out;

    // 1) in_proj (bf16 MFMA): XZ[e,l] = W(4096,1024) x x(1024,1024)^T
    hipLaunchKernelGGL(cvt_k, dim3((4096 * 1024 / 4) / 256), dim3(256), 0, stream,
                       in_proj_w, WB, 4096 * 1024 / 4);
    hipLaunchKernelGGL(cvt_k, dim3((1024 * 1024 / 4) / 256), dim3(256), 0, stream,
                       x, XB, 1024 * 1024 / 4);
    hipLaunchKernelGGL(mfma_nt_k, dim3(8, 32), dim3(256), 0, stream,
                       WB, XB, XZ, 4096, 1024, 1024);

    // 2) in_proj1 (bf16 MFMA): X1P[e,l]
    hipLaunchKernelGGL(cvt_k, dim3((2048 * 1024 / 4) / 256), dim3(256), 0, stream,
                       in_proj1_w, WB1, 2048 * 1024 / 4);
    hipLaunchKernelGGL(cvt_k, dim3((1024 * 1024 / 4) / 256), dim3(256), 0, stream,
                       x1, X1B, 1024 * 1024 / 4);
    hipLaunchKernelGGL(mfma_nt_k, dim3(8, 16), dim3(256), 0, stream,
                       WB1, X1B, X1P, 2048, 1024, 1024);

    // 3) causal conv + silu
    hipLaunchKernelGGL(conv_silu_k, dim3(2 * D_INNER * LSEQ / 256), dim3(256), 0, stream,
                       XA, X1P, conv_w, conv_b, conv1_w, conv1_b, CO0, CO1);

    // 4) x_proj (fp32): xdbl[k,l] = W(96,2048) @ co(2048,1024)
    {
        dim3 g(LSEQ / TS, (96 + TS - 1) / TS);
        hipLaunchKernelGGL(sgemm_k<false>, g, dim3(256), 0, stream,
                           x_proj_w, CO0, nullptr, XDBL0, 96, LSEQ, D_INNER, 0);
        hipLaunchKernelGGL(sgemm_k<false>, g, dim3(256), 0, stream,
                           x_proj1_w, CO1, nullptr, XDBL1, 96, LSEQ, D_INNER, 0);
    }

    // 5) dt_proj (fp32): delta[e,l] = W(2048,64) @ xdbl[:64] (overwrites dead WB1/X1B)
    {
        dim3 g(LSEQ / TS, D_INNER / TS);
        hipLaunchKernelGGL(sgemm_k<false>, g, dim3(256), 0, stream,
                           dt_proj_w, XDBL0, nullptr, DELTA0, D_INNER, LSEQ, DT_RANK, 0);
        hipLaunchKernelGGL(sgemm_k<false>, g, dim3(256), 0, stream,
                           dt_proj1_w, XDBL1, nullptr, DELTA1, D_INNER, LSEQ, DT_RANK, 0);
    }

    // 6) prep: sp = softplus(delta) in place; gz = silu(z) into dead xa
    hipLaunchKernelGGL(prep_k, dim3(3 * (D_INNER * LSEQ / 4) / 256), dim3(256), 0, stream,
                       DELTA0, DELTA1, Zg, GZ);

    // 7) chunk-parallel scan, res in place over co
    hipLaunchKernelGGL(scan3_k, dim3(D_INNER, 2), dim3(256), 0, stream,
                       DELTA0, CO0, XDBL0, A_log, Dskip,
                       DELTA1, CO1, XDBL1, A_log1, Dskip1,
                       GZ, RES0, RES1);

    // 8) REST[l,d] = bf16(res0+res1); OWB = bf16(out_proj_w)  (over dead sp region)
    hipLaunchKernelGGL(cvt_k, dim3((1024 * 2048 / 4) / 256), dim3(256), 0, stream,
                       out_proj_w, OWB, 1024 * 2048 / 4);
    hipLaunchKernelGGL(cvtT_add_k, dim3(LSEQ / 32, D_INNER / 32), dim3(256), 0, stream,
                       RES0, RES1, RESTB);

    // 9) out_proj (bf16 MFMA): out[l,e] = REST(1024,2048) x OW(1024,2048)^T
    hipLaunchKernelGGL(mfma_nt_k, dim3(8, 8), dim3(256), 0, stream,
                       RESTB, OWB, out, 1024, 1024, 2048);
}

// Round 5
// 547.718 us; speedup vs baseline: 4.2338x; 1.0439x over previous
//
#include <hip/hip_runtime.h>
#include <hip/hip_bf16.h>
#include <math.h>

// ---------------- problem constants ----------------
#define D_MODEL 1024
#define D_STATE 16
#define D_CONV  4
#define D_INNER 2048
#define DT_RANK 64
#define LSEQ    1024

typedef short bf16x8 __attribute__((ext_vector_type(8)));
typedef float f32x4  __attribute__((ext_vector_type(4)));

// fast device math: native v_exp_f32 / v_log_f32
__device__ __forceinline__ float softplus_f(float x) {
    const float sp = __logf(1.f + __expf(x));
    return (x > 20.f) ? x : sp;
}
__device__ __forceinline__ float silu_f(float x) {
    return x / (1.f + __expf(-x));
}
// fp32 -> bf16 round-to-nearest-even
__device__ __forceinline__ unsigned short f2bf(float f) {
    union { float f; unsigned int u; } c; c.f = f;
    const unsigned int u = c.u;
    return (unsigned short)((u + 0x7FFFu + ((u >> 16) & 1u)) >> 16);
}

// ---------------- elementwise fp32 -> bf16 convert ----------------
__global__ __launch_bounds__(256)
void cvt_k(const float* __restrict__ in, unsigned short* __restrict__ out, int n4)
{
    const int i = blockIdx.x * 256 + threadIdx.x;
    if (i >= n4) return;
    const float4 v = *(const float4*)&in[(size_t)i * 4];
    ushort4 o;
    o.x = f2bf(v.x); o.y = f2bf(v.y); o.z = f2bf(v.z); o.w = f2bf(v.w);
    *(ushort4*)&out[(size_t)i * 4] = o;
}

// ---------------- transpose + add + convert: REST[l][d] = bf16(res0[d][l]+res1[d][l]) ----
__global__ __launch_bounds__(256)
void cvtT_add_k(const float* __restrict__ r0, const float* __restrict__ r1,
                unsigned short* __restrict__ dst)
{
    __shared__ float s[32][33];
    const int tx = threadIdx.x & 31, ty = threadIdx.x >> 5;   // 32 x 8
    const int dBase = blockIdx.y * 32, lBase = blockIdx.x * 32;
    #pragma unroll
    for (int i = 0; i < 4; ++i) {
        const int d = dBase + ty + i * 8;
        const size_t off = (size_t)d * LSEQ + lBase + tx;
        s[ty + i * 8][tx] = r0[off] + r1[off];
    }
    __syncthreads();
    #pragma unroll
    for (int i = 0; i < 4; ++i) {
        const int l = lBase + ty + i * 8;
        dst[(size_t)l * D_INNER + dBase + tx] = f2bf(s[tx][ty + i * 8]);
    }
}

// ---------------- bf16 MFMA GEMM, NT layout ----------------
// C[m,n] = sum_k A[m*K+k] * B[n*K+k]; A (M,K) bf16, B (N,K) bf16, C (M,N) f32.
// 128x128 tile, 4 waves (2x2), each wave 64x64 = 4x4 frags of 16x16x32.
// Rows >= siluRow get silu applied on store (fuses gate-branch activation).
__global__ __launch_bounds__(256)
void mfma_nt_k(const unsigned short* __restrict__ A, const unsigned short* __restrict__ B,
               float* __restrict__ C, int M, int N, int K, int siluRow)
{
    __shared__ unsigned short As[128][40];   // +8 pad
    __shared__ unsigned short Bs[128][40];
    const int tid = threadIdx.x;
    const int mBase = blockIdx.y * 128, nBase = blockIdx.x * 128;
    const int lane = tid & 63, w = tid >> 6;
    const int wr = w >> 1, wc = w & 1;
    const int l15 = lane & 15, l4 = lane >> 4;

    f32x4 acc[4][4] = {};

    const int sr = tid >> 2;        // 0..63
    const int sk = (tid & 3) * 8;   // 0,8,16,24

    for (int kb = 0; kb < K; kb += 32) {
        #pragma unroll
        for (int it = 0; it < 2; ++it) {
            const int r = it * 64 + sr;
            const float4 va = *(const float4*)&A[(size_t)(mBase + r) * K + kb + sk];
            *(float4*)&As[r][sk] = va;
            const float4 vb = *(const float4*)&B[(size_t)(nBase + r) * K + kb + sk];
            *(float4*)&Bs[r][sk] = vb;
        }
        __syncthreads();
        bf16x8 af[4], bfr[4];
        #pragma unroll
        for (int i = 0; i < 4; ++i) {
            af[i]  = *(const bf16x8*)&As[wr * 64 + i * 16 + l15][l4 * 8];
            bfr[i] = *(const bf16x8*)&Bs[wc * 64 + i * 16 + l15][l4 * 8];
        }
        #pragma unroll
        for (int i = 0; i < 4; ++i)
            #pragma unroll
            for (int j = 0; j < 4; ++j)
                acc[i][j] = __builtin_amdgcn_mfma_f32_16x16x32_bf16(af[i], bfr[j], acc[i][j], 0, 0, 0);
        __syncthreads();
    }

    #pragma unroll
    for (int i = 0; i < 4; ++i) {
        const int row0 = mBase + wr * 64 + i * 16 + l4 * 4;
        #pragma unroll
        for (int j = 0; j < 4; ++j) {
            const int col = nBase + wc * 64 + j * 16 + l15;
            #pragma unroll
            for (int r = 0; r < 4; ++r) {
                float v = acc[i][j][r];
                if (row0 + r >= siluRow) v = silu_f(v);
                C[(size_t)(row0 + r) * N + col] = v;
            }
        }
    }
}

// ---------------- tiled fp32 GEMM (x_proj split-K partials, dt_proj) ----------------
constexpr int TS = 64;
constexpr int KT = 16;
constexpr int LP = 4;

// BNT=true : B (N,K)-ish row-major with leading dim ldb -> B[n*ldb+k]
// BNT=false: B (K,N) row-major ldb -> B[k*ldb+n]
// act: 0 none, 1 softplus on store. Store C[m*N+n] (+ blockIdx.z K-slicing by caller ptr offset).
template<bool BNT>
__global__ __launch_bounds__(256)
void sgemm2_k(const float* __restrict__ A, const float* __restrict__ B,
              float* __restrict__ C, int M, int N, int K, int lda, int ldb, int act)
{
    __shared__ float As[KT][TS + LP];
    __shared__ float Bs[KT][TS + LP];
    const int tid = threadIdx.x;
    const int tx = tid & 15, ty = tid >> 4;
    const int mBase = blockIdx.y * TS;
    const int nBase = blockIdx.x * TS;

    float acc[4][4] = {};

    const int ar = tid >> 2;
    const int ak = (tid & 3) * 4;

    for (int kb = 0; kb < K; kb += KT) {
        {
            const int gm = mBase + ar;
            float4 av = make_float4(0.f, 0.f, 0.f, 0.f);
            if (gm < M) av = *(const float4*)&A[(size_t)gm * lda + kb + ak];
            As[ak + 0][ar] = av.x;
            As[ak + 1][ar] = av.y;
            As[ak + 2][ar] = av.z;
            As[ak + 3][ar] = av.w;
        }
        if (BNT) {
            const int gn = nBase + ar;
            float4 bv = make_float4(0.f, 0.f, 0.f, 0.f);
            if (gn < N) bv = *(const float4*)&B[(size_t)gn * ldb + kb + ak];
            Bs[ak + 0][ar] = bv.x;
            Bs[ak + 1][ar] = bv.y;
            Bs[ak + 2][ar] = bv.z;
            Bs[ak + 3][ar] = bv.w;
        } else {
            const int bk = tid >> 4;
            const int bn = (tid & 15) * 4;
            const float4 bv = *(const float4*)&B[(size_t)(kb + bk) * ldb + nBase + bn];
            *(float4*)&Bs[bk][bn] = bv;
        }
        __syncthreads();

        #pragma unroll
        for (int k = 0; k < KT; ++k) {
            float4 a = *(const float4*)&As[k][ty * 4];
            float4 b = *(const float4*)&Bs[k][tx * 4];
            float av[4] = {a.x, a.y, a.z, a.w};
            float bv[4] = {b.x, b.y, b.z, b.w};
            #pragma unroll
            for (int i = 0; i < 4; ++i)
                #pragma unroll
                for (int j = 0; j < 4; ++j)
                    acc[i][j] = fmaf(av[i], bv[j], acc[i][j]);
        }
        __syncthreads();
    }

    #pragma unroll
    for (int i = 0; i < 4; ++i) {
        const int m = mBase + ty * 4 + i;
        if (m >= M) continue;
        #pragma unroll
        for (int j = 0; j < 4; ++j) {
            const int n = nBase + tx * 4 + j;
            if (n >= N) continue;
            float v = acc[i][j];
            if (act == 1) v = softplus_f(v);
            C[(size_t)m * N + n] = v;
        }
    }
}

// ---------------- reduce split-K partials + transpose + interleave B/C ----------------
// P layout per branch: [8][96][LSEQ]. Output xdT [LSEQ][96]:
//   cols 0..63 = delta-rank rows 0..63; col 64+2n = B_n (row 64+n); col 65+2n = C_n (row 80+n).
__global__ __launch_bounds__(256)
void reduceT_k(const float* __restrict__ P0, const float* __restrict__ P1,
               float* __restrict__ xdT0, float* __restrict__ xdT1)
{
    const int idx = blockIdx.x * 256 + threadIdx.x;   // 2 * 1024 * 128
    const int k = idx & 127;
    const int l = (idx >> 7) & (LSEQ - 1);
    const int br = idx >> 17;
    if (k >= 96) return;
    const int srck = (k < 64) ? k : (64 + ((k - 64) >> 1) + ((k & 1) << 4));
    const float* P = br ? P1 : P0;
    float s = 0.f;
    #pragma unroll
    for (int sl = 0; sl < 8; ++sl)
        s += P[(size_t)sl * 96 * LSEQ + (size_t)srck * LSEQ + l];
    float* o = br ? xdT1 : xdT0;
    o[(size_t)l * 96 + k] = s;
}

// ---------------- depthwise causal conv1d + SiLU (both branches) ----------------
__global__ __launch_bounds__(256)
void conv_silu_k(const float* __restrict__ xa, const float* __restrict__ x1p,
                 const float* __restrict__ w0, const float* __restrict__ b0,
                 const float* __restrict__ w1, const float* __restrict__ b1,
                 float* __restrict__ co0, float* __restrict__ co1)
{
    const int idx = blockIdx.x * blockDim.x + threadIdx.x;
    const int br  = idx >> 21;
    const int rem = idx & ((1 << 21) - 1);
    const int d = rem >> 10;
    const int l = rem & (LSEQ - 1);

    const float* xin = br ? x1p : xa;
    const float* w   = br ? w1 : w0;
    const float* bb  = br ? b1 : b0;
    float* out       = br ? co1 : co0;

    const float* row = xin + (size_t)d * LSEQ;
    float acc = bb[d];
    #pragma unroll
    for (int j = 0; j < D_CONV; ++j) {
        const int li = l - (D_CONV - 1) + j;
        const float xv = (li >= 0) ? row[li] : 0.f;
        acc = fmaf(w[d * D_CONV + j], xv, acc);
    }
    out[rem] = silu_f(acc);
}

// ---------------- chunk-parallel selective scan ----------------
// sp = softplus(delta) [d][L]; u = co [d][L] (res written in place -> no restrict);
// xdT = [L][96] with B/C interleaved at cols 64+2n / 65+2n; gz = silu(z) [d][L].
__global__ __launch_bounds__(256)
void scan4_k(const float* sp0, const float* u0, const float* xdT0,
             const float* Al0, const float* Dk0,
             const float* sp1, const float* u1, const float* xdT1,
             const float* Al1, const float* Dk1,
             const float* gz, float* res0, float* res1)
{
    const int d   = blockIdx.x;
    const int br  = blockIdx.y;
    const int tid = threadIdx.x;
    const int n   = tid & 15;
    const int c   = tid >> 4;

    const float* sp  = br ? sp1  : sp0;
    const float* u   = br ? u1   : u0;
    const float* xdT = br ? xdT1 : xdT0;
    const float* Al  = br ? Al1  : Al0;
    const float* Dk  = br ? Dk1  : Dk0;
    float* res       = br ? res1 : res0;

    const float Adn = -__expf(Al[d * D_STATE + n]);
    const float Dd  = Dk[d];

    const float* srow = sp + (size_t)d * LSEQ;
    const float* urow = u  + (size_t)d * LSEQ;
    const float* grow = gz + (size_t)d * LSEQ;
    const float* bc   = xdT + 64 + 2 * n;     // + t*96
    float* orow = res + (size_t)d * LSEQ;

    const int t0 = c * 64;

    // ---- phase 1: chunk-local (a, b)
    float a = 1.f, b = 0.f;
    for (int tt = 0; tt < 64; tt += 4) {
        const float4 s4 = *(const float4*)&srow[t0 + tt];
        const float4 u4 = *(const float4*)&urow[t0 + tt];
        const float sps[4] = {s4.x, s4.y, s4.z, s4.w};
        const float uvs[4] = {u4.x, u4.y, u4.z, u4.w};
        #pragma unroll
        for (int j = 0; j < 4; ++j) {
            const float2 bcv = *(const float2*)&bc[(size_t)(t0 + tt + j) * 96];
            const float dA = __expf(sps[j] * Adn);
            a *= dA;
            b = fmaf(dA, b, sps[j] * uvs[j] * bcv.x);
        }
    }

    __shared__ float sAm[16][16];
    __shared__ float sBm[16][16];
    __shared__ float sHm[16][16];
    sAm[c][n] = a;
    sBm[c][n] = b;
    __syncthreads();

    // ---- phase 2: serial scan over chunks
    if (tid < 16) {
        float hb = 0.f;
        #pragma unroll
        for (int cc = 0; cc < 16; ++cc) {
            sHm[cc][tid] = hb;
            hb = fmaf(sAm[cc][tid], hb, sBm[cc][tid]);
        }
    }
    __syncthreads();

    // ---- phase 3: re-run chunk from h_start, emit y
    float h = sHm[c][n];
    for (int tt = 0; tt < 64; tt += 4) {
        const float4 s4 = *(const float4*)&srow[t0 + tt];
        const float4 u4 = *(const float4*)&urow[t0 + tt];
        const float4 g4 = *(const float4*)&grow[t0 + tt];
        const float sps[4] = {s4.x, s4.y, s4.z, s4.w};
        const float uvs[4] = {u4.x, u4.y, u4.z, u4.w};
        const float gzs[4] = {g4.x, g4.y, g4.z, g4.w};
        float y4[4];
        #pragma unroll
        for (int j = 0; j < 4; ++j) {
            const float2 bcv = *(const float2*)&bc[(size_t)(t0 + tt + j) * 96];
            const float dA = __expf(sps[j] * Adn);
            h = fmaf(dA, h, sps[j] * uvs[j] * bcv.x);
            float y = h * bcv.y;
            y += __shfl_xor(y, 1);
            y += __shfl_xor(y, 2);
            y += __shfl_xor(y, 4);
            y += __shfl_xor(y, 8);
            y4[j] = y;
        }
        if (n == 0) {
            float4 o;
            float* op = (float*)&o;
            #pragma unroll
            for (int j = 0; j < 4; ++j)
                op[j] = (y4[j] + Dd * uvs[j]) * gzs[j];
            *(float4*)&orow[t0 + tt] = o;
        }
    }
}

// ---------------- launcher ----------------
extern "C" void kernel_launch(void* const* d_in, const int* in_sizes, int n_in,
                              void* d_out, int out_size, void* d_ws, size_t ws_size,
                              hipStream_t stream)
{
    const float* x          = (const float*)d_in[0];
    const float* x1         = (const float*)d_in[1];
    const float* in_proj_w  = (const float*)d_in[2];
    const float* in_proj1_w = (const float*)d_in[3];
    const float* conv_w     = (const float*)d_in[4];
    const float* conv_b     = (const float*)d_in[5];
    const float* conv1_w    = (const float*)d_in[6];
    const float* conv1_b    = (const float*)d_in[7];
    const float* x_proj_w   = (const float*)d_in[8];
    const float* x_proj1_w  = (const float*)d_in[9];
    const float* dt_proj_w  = (const float*)d_in[10];
    const float* dt_proj1_w = (const float*)d_in[11];
    const float* A_log      = (const float*)d_in[12];
    const float* A_log1     = (const float*)d_in[13];
    const float* Dskip      = (const float*)d_in[14];
    const float* Dskip1     = (const float*)d_in[15];
    const float* out_proj_w = (const float*)d_in[16];

    float* ws = (float*)d_ws;
    const size_t CH = (size_t)D_INNER * LSEQ;        // 2 Mi f32
    const size_t XD = (size_t)96 * LSEQ;             // 96 Ki f32
    const size_t F  = 5 * CH + 2 * XD;               // scratch region base

    // layout (f32 units), total = 7*CH + 2*XD (same footprint as round 4):
    //   [0,CH)        xa (conv input)          -> dead after conv
    //   [CH,2CH)      z, silu'd by in_proj epilogue (= gz)
    //   [2CH,3CH)     x1p (dead after conv)
    //   [3CH,4CH)     co0 -> res0 (in place)
    //   [4CH,5CH)     co1 -> res1 (in place)
    //   [5CH,5CH+2XD) xdT0, xdT1  ([L][96] transposed+interleaved)
    //   [F,F+2CH)     time-sliced: {WB,XB} -> {WB1,X1B} -> {P0,P1} -> {sp0,sp1} -> {OWB,RESTB}
    float* XA    = ws;
    float* GZ    = ws + CH;              // silu(z), produced by in_proj epilogue
    float* X1P   = ws + 2 * CH;
    float* CO0   = ws + 3 * CH;
    float* CO1   = ws + 4 * CH;
    float* RES0  = CO0;                  // in-place
    float* RES1  = CO1;                  // in-place
    float* XDT0  = ws + 5 * CH;
    float* XDT1  = XDT0 + XD;
    float* P0    = ws + F;               // 8*96*1024 = 768K f32
    float* P1    = P0 + 8 * XD;
    float* SP0   = ws + F;               // softplus(delta), overwrites dead P
    float* SP1   = ws + F + CH;
    float* XZ    = ws;                   // [0,2CH): in_proj output (xa | z)

    unsigned short* WB    = (unsigned short*)(ws + F);            // 4096x1024 bf16
    unsigned short* XB    = (unsigned short*)(ws + F + CH);       // 1024x1024 bf16
    unsigned short* WB1   = (unsigned short*)(ws + F);            // 2048x1024 bf16
    unsigned short* X1B   = (unsigned short*)(ws + F + CH / 2);   // 1024x1024 bf16
    unsigned short* OWB   = (unsigned short*)(ws + F);            // 1024x2048 bf16
    unsigned short* RESTB = (unsigned short*)(ws + F + CH / 2);   // 1024x2048 bf16

    float* out = (float*)d_out;
    const int BIG = 1 << 30;

    // 1) in_proj (bf16 MFMA): XZ[e,l]; rows >= 2048 (z) get silu in epilogue
    hipLaunchKernelGGL(cvt_k, dim3((4096 * 1024 / 4) / 256), dim3(256), 0, stream,
                       in_proj_w, WB, 4096 * 1024 / 4);
    hipLaunchKernelGGL(cvt_k, dim3((1024 * 1024 / 4) / 256), dim3(256), 0, stream,
                       x, XB, 1024 * 1024 / 4);
    hipLaunchKernelGGL(mfma_nt_k, dim3(8, 32), dim3(256), 0, stream,
                       WB, XB, XZ, 4096, 1024, 1024, 2048);

    // 2) in_proj1 (bf16 MFMA): X1P[e,l]
    hipLaunchKernelGGL(cvt_k, dim3((2048 * 1024 / 4) / 256), dim3(256), 0, stream,
                       in_proj1_w, WB1, 2048 * 1024 / 4);
    hipLaunchKernelGGL(cvt_k, dim3((1024 * 1024 / 4) / 256), dim3(256), 0, stream,
                       x1, X1B, 1024 * 1024 / 4);
    hipLaunchKernelGGL(mfma_nt_k, dim3(8, 16), dim3(256), 0, stream,
                       WB1, X1B, X1P, 2048, 1024, 1024, BIG);

    // 3) causal conv + silu
    hipLaunchKernelGGL(conv_silu_k, dim3(2 * D_INNER * LSEQ / 256), dim3(256), 0, stream,
                       XA, X1P, conv_w, conv_b, conv1_w, conv1_b, CO0, CO1);

    // 4) x_proj split-K (fp32): P[s][k][l] partial over K-slice of 256
    {
        dim3 g(LSEQ / TS, 2, 8);   // 16 l-tiles x 2 m-tiles(96) x 8 k-slices
        for (int s = 0; s < 8; ++s) {
            // fold slice into z via separate launches? keep one 3D launch instead:
        }
        // single 3D-grid launches (blockIdx.z = k-slice), C offset via P + z*96*L handled in-kernel
        // -> simpler: loop z on host into the same graph (8 small launches per branch is fine)
        for (int s = 0; s < 8; ++s) {
            hipLaunchKernelGGL(sgemm2_k<false>, dim3(LSEQ / TS, 2), dim3(256), 0, stream,
                               x_proj_w + s * 256, CO0 + (size_t)s * 256 * LSEQ,
                               P0 + (size_t)s * 96 * LSEQ, 96, LSEQ, 256, D_INNER, LSEQ, 0);
            hipLaunchKernelGGL(sgemm2_k<false>, dim3(LSEQ / TS, 2), dim3(256), 0, stream,
                               x_proj1_w + s * 256, CO1 + (size_t)s * 256 * LSEQ,
                               P1 + (size_t)s * 96 * LSEQ, 96, LSEQ, 256, D_INNER, LSEQ, 0);
        }
    }

    // 5) reduce partials -> xdT [L][96], B/C interleaved
    hipLaunchKernelGGL(reduceT_k, dim3(2 * LSEQ * 128 / 256), dim3(256), 0, stream,
                       P0, P1, XDT0, XDT1);

    // 6) dt_proj (fp32 NT, ldb=96) + fused softplus -> SP[e][l] (overwrites dead P)
    {
        dim3 g(LSEQ / TS, D_INNER / TS);
        hipLaunchKernelGGL(sgemm2_k<true>, g, dim3(256), 0, stream,
                           dt_proj_w, XDT0, SP0, D_INNER, LSEQ, DT_RANK, DT_RANK, 96, 1);
        hipLaunchKernelGGL(sgemm2_k<true>, g, dim3(256), 0, stream,
                           dt_proj1_w, XDT1, SP1, D_INNER, LSEQ, DT_RANK, DT_RANK, 96, 1);
    }

    // 7) chunk-parallel scan, res in place over co
    hipLaunchKernelGGL(scan4_k, dim3(D_INNER, 2), dim3(256), 0, stream,
                       SP0, CO0, XDT0, A_log, Dskip,
                       SP1, CO1, XDT1, A_log1, Dskip1,
                       GZ, RES0, RES1);

    // 8) REST[l,d] = bf16(res0+res1); OWB = bf16(out_proj_w) (over dead SP region)
    hipLaunchKernelGGL(cvt_k, dim3((1024 * 2048 / 4) / 256), dim3(256), 0, stream,
                       out_proj_w, OWB, 1024 * 2048 / 4);
    hipLaunchKernelGGL(cvtT_add_k, dim3(LSEQ / 32, D_INNER / 32), dim3(256), 0, stream,
                       RES0, RES1, RESTB);

    // 9) out_proj (bf16 MFMA): out[l,e] = REST(1024,2048) x OW(1024,2048)^T
    hipLaunchKernelGGL(mfma_nt_k, dim3(8, 8), dim3(256), 0, stream,
                       RESTB, OWB, out, 1024, 1024, 2048, BIG);
}

// Round 6
// 253.769 us; speedup vs baseline: 9.1379x; 2.1583x over previous
//
#include <hip/hip_runtime.h>
#include <hip/hip_bf16.h>
#include <math.h>

// ---------------- problem constants ----------------
#define D_MODEL 1024
#define D_STATE 16
#define D_CONV  4
#define D_INNER 2048
#define DT_RANK 64
#define LSEQ    1024

typedef short bf16x8 __attribute__((ext_vector_type(8)));
typedef float f32x4  __attribute__((ext_vector_type(4)));

__device__ __forceinline__ float softplus_f(float x) {
    const float sp = __logf(1.f + __expf(x));
    return (x > 20.f) ? x : sp;
}
__device__ __forceinline__ float silu_f(float x) {
    return x / (1.f + __expf(-x));
}
__device__ __forceinline__ unsigned short f2bf(float f) {
    union { float f; unsigned int u; } c; c.f = f;
    const unsigned int u = c.u;
    return (unsigned short)((u + 0x7FFFu + ((u >> 16) & 1u)) >> 16);
}

// ---------------- fused fp32->bf16 convert of all 4 GEMM inputs ----------------
// groups of 4 floats: [0,1M) in_proj_w->WB; [1M,1.25M) x->XB; [1.25M,1.75M) in_proj1_w->WB1; [1.75M,2M) x1->X1B
__global__ __launch_bounds__(256)
void cvt_all_k(const float* __restrict__ w0, const float* __restrict__ xx,
               const float* __restrict__ w1, const float* __restrict__ xx1,
               unsigned short* __restrict__ WB, unsigned short* __restrict__ XB,
               unsigned short* __restrict__ WB1, unsigned short* __restrict__ X1B)
{
    const int i = blockIdx.x * 256 + threadIdx.x;
    const float* src; unsigned short* dst; int j;
    if (i < (1 << 20))            { src = w0;  dst = WB;  j = i; }
    else if (i < (5 << 18))       { src = xx;  dst = XB;  j = i - (1 << 20); }
    else if (i < (7 << 18))       { src = w1;  dst = WB1; j = i - (5 << 18); }
    else                          { src = xx1; dst = X1B; j = i - (7 << 18); }
    const float4 v = *(const float4*)&src[(size_t)j * 4];
    ushort4 o;
    o.x = f2bf(v.x); o.y = f2bf(v.y); o.z = f2bf(v.z); o.w = f2bf(v.w);
    *(ushort4*)&dst[(size_t)j * 4] = o;
}

__global__ __launch_bounds__(256)
void cvt_k(const float* __restrict__ in, unsigned short* __restrict__ out, int n4)
{
    const int i = blockIdx.x * 256 + threadIdx.x;
    if (i >= n4) return;
    const float4 v = *(const float4*)&in[(size_t)i * 4];
    ushort4 o;
    o.x = f2bf(v.x); o.y = f2bf(v.y); o.z = f2bf(v.z); o.w = f2bf(v.w);
    *(ushort4*)&out[(size_t)i * 4] = o;
}

// ---------------- transpose + add + convert: REST[l][d] = bf16(res0[d][l]+res1[d][l]) ----
__global__ __launch_bounds__(256)
void cvtT_add_k(const float* __restrict__ r0, const float* __restrict__ r1,
                unsigned short* __restrict__ dst)
{
    __shared__ float s[32][33];
    const int tx = threadIdx.x & 31, ty = threadIdx.x >> 5;
    const int dBase = blockIdx.y * 32, lBase = blockIdx.x * 32;
    #pragma unroll
    for (int i = 0; i < 4; ++i) {
        const int d = dBase + ty + i * 8;
        const size_t off = (size_t)d * LSEQ + lBase + tx;
        s[ty + i * 8][tx] = r0[off] + r1[off];
    }
    __syncthreads();
    #pragma unroll
    for (int i = 0; i < 4; ++i) {
        const int l = lBase + ty + i * 8;
        dst[(size_t)l * D_INNER + dBase + tx] = f2bf(s[tx][ty + i * 8]);
    }
}

// ---------------- bf16 MFMA GEMM core (NT), 128x128 tile, 4 waves ----------------
__device__ __forceinline__
void mfma_tile(const unsigned short* __restrict__ A, const unsigned short* __restrict__ B,
               float* __restrict__ C, int N, int K, int mBase, int nBase, int siluRow)
{
    __shared__ unsigned short As[128][40];
    __shared__ unsigned short Bs[128][40];
    const int tid = threadIdx.x;
    const int lane = tid & 63, w = tid >> 6;
    const int wr = w >> 1, wc = w & 1;
    const int l15 = lane & 15, l4 = lane >> 4;

    f32x4 acc[4][4] = {};
    const int sr = tid >> 2;
    const int sk = (tid & 3) * 8;

    for (int kb = 0; kb < K; kb += 32) {
        #pragma unroll
        for (int it = 0; it < 2; ++it) {
            const int r = it * 64 + sr;
            const float4 va = *(const float4*)&A[(size_t)(mBase + r) * K + kb + sk];
            *(float4*)&As[r][sk] = va;
            const float4 vb = *(const float4*)&B[(size_t)(nBase + r) * K + kb + sk];
            *(float4*)&Bs[r][sk] = vb;
        }
        __syncthreads();
        bf16x8 af[4], bfr[4];
        #pragma unroll
        for (int i = 0; i < 4; ++i) {
            af[i]  = *(const bf16x8*)&As[wr * 64 + i * 16 + l15][l4 * 8];
            bfr[i] = *(const bf16x8*)&Bs[wc * 64 + i * 16 + l15][l4 * 8];
        }
        #pragma unroll
        for (int i = 0; i < 4; ++i)
            #pragma unroll
            for (int j = 0; j < 4; ++j)
                acc[i][j] = __builtin_amdgcn_mfma_f32_16x16x32_bf16(af[i], bfr[j], acc[i][j], 0, 0, 0);
        __syncthreads();
    }

    #pragma unroll
    for (int i = 0; i < 4; ++i) {
        const int row0 = mBase + wr * 64 + i * 16 + l4 * 4;
        #pragma unroll
        for (int j = 0; j < 4; ++j) {
            const int col = nBase + wc * 64 + j * 16 + l15;
            #pragma unroll
            for (int r = 0; r < 4; ++r) {
                float v = acc[i][j][r];
                if (row0 + r >= siluRow) v = silu_f(v);
                C[(size_t)(row0 + r) * N + col] = v;
            }
        }
    }
}

// merged in_proj + in_proj1: grid (8, 48); y<32 -> branch0 (silu on z rows), else branch1
__global__ __launch_bounds__(256)
void mfma_in_k(const unsigned short* __restrict__ WB, const unsigned short* __restrict__ XB,
               const unsigned short* __restrict__ WB1, const unsigned short* __restrict__ X1B,
               float* __restrict__ XZ, float* __restrict__ X1P)
{
    const int by = blockIdx.y;
    if (by < 32)
        mfma_tile(WB, XB, XZ, 1024, 1024, by * 128, blockIdx.x * 128, 2048);
    else
        mfma_tile(WB1, X1B, X1P, 1024, 1024, (by - 32) * 128, blockIdx.x * 128, 1 << 30);
}

// out_proj: grid (8, 8)
__global__ __launch_bounds__(256)
void mfma_out_k(const unsigned short* __restrict__ RESTB, const unsigned short* __restrict__ OWB,
                float* __restrict__ C)
{
    mfma_tile(RESTB, OWB, C, 1024, 2048, blockIdx.y * 128, blockIdx.x * 128, 1 << 30);
}

// ---------------- x_proj split-K, single launch ----------------
// grid (16, 2, 16): x = l-tile, y = k-row-tile (96 rows in 2x64), z = branch*8 + slice
// P[branch][slice][96][LSEQ] partial over K-slice of 256.
constexpr int TS = 64;
constexpr int KT = 16;
constexpr int LP = 4;

__global__ __launch_bounds__(256)
void xproj_k(const float* __restrict__ xw0, const float* __restrict__ co0,
             const float* __restrict__ xw1, const float* __restrict__ co1,
             float* __restrict__ P0, float* __restrict__ P1)
{
    const int br = blockIdx.z >> 3;
    const int sl = blockIdx.z & 7;
    const float* A = (br ? xw1 : xw0) + sl * 256;            // (96, 2048) slice cols
    const float* B = (br ? co1 : co0) + (size_t)sl * 256 * LSEQ;  // (256, LSEQ) slice rows
    float* C = (br ? P1 : P0) + (size_t)sl * 96 * LSEQ;

    __shared__ float As[KT][TS + LP];
    __shared__ float Bs[KT][TS + LP];
    const int tid = threadIdx.x;
    const int tx = tid & 15, ty = tid >> 4;
    const int mBase = blockIdx.y * TS;
    const int nBase = blockIdx.x * TS;

    float acc[4][4] = {};
    const int ar = tid >> 2;
    const int ak = (tid & 3) * 4;

    for (int kb = 0; kb < 256; kb += KT) {
        {
            const int gm = mBase + ar;
            float4 av = make_float4(0.f, 0.f, 0.f, 0.f);
            if (gm < 96) av = *(const float4*)&A[(size_t)gm * D_INNER + kb + ak];
            As[ak + 0][ar] = av.x;
            As[ak + 1][ar] = av.y;
            As[ak + 2][ar] = av.z;
            As[ak + 3][ar] = av.w;
        }
        {
            const int bk = tid >> 4;
            const int bn = (tid & 15) * 4;
            const float4 bv = *(const float4*)&B[(size_t)(kb + bk) * LSEQ + nBase + bn];
            *(float4*)&Bs[bk][bn] = bv;
        }
        __syncthreads();
        #pragma unroll
        for (int k = 0; k < KT; ++k) {
            float4 a = *(const float4*)&As[k][ty * 4];
            float4 b = *(const float4*)&Bs[k][tx * 4];
            float av[4] = {a.x, a.y, a.z, a.w};
            float bv[4] = {b.x, b.y, b.z, b.w};
            #pragma unroll
            for (int i = 0; i < 4; ++i)
                #pragma unroll
                for (int j = 0; j < 4; ++j)
                    acc[i][j] = fmaf(av[i], bv[j], acc[i][j]);
        }
        __syncthreads();
    }

    #pragma unroll
    for (int i = 0; i < 4; ++i) {
        const int m = mBase + ty * 4 + i;
        if (m >= 96) continue;
        #pragma unroll
        for (int j = 0; j < 4; ++j)
            C[(size_t)m * LSEQ + nBase + tx * 4 + j] = acc[i][j];
    }
}

// ---------------- reduce split-K partials + transpose + interleave B/C ----------------
// out xdT [LSEQ][96]: cols 0..63 = dt-rank; col 64+2n = B_n (row 64+n); col 65+2n = C_n (row 80+n).
__global__ __launch_bounds__(256)
void reduceT_k(const float* __restrict__ P0, const float* __restrict__ P1,
               float* __restrict__ xdT0, float* __restrict__ xdT1)
{
    const int idx = blockIdx.x * 256 + threadIdx.x;
    const int k = idx & 127;
    const int l = (idx >> 7) & (LSEQ - 1);
    const int br = idx >> 17;
    if (k >= 96) return;
    const int srck = (k < 64) ? k : (64 + ((k - 64) >> 1) + ((k & 1) << 4));
    const float* P = br ? P1 : P0;
    float s = 0.f;
    #pragma unroll
    for (int sl = 0; sl < 8; ++sl)
        s += P[(size_t)sl * 96 * LSEQ + (size_t)srck * LSEQ + l];
    float* o = br ? xdT1 : xdT0;
    o[(size_t)l * 96 + k] = s;
}

// ---------------- dt_proj (both branches, one launch) + fused softplus ----------------
// grid (16, 32, 2). SP[e][l] = softplus(sum_k dtw[e][k] * xdT[l][64..? no: cols 0..63]).
__global__ __launch_bounds__(256)
void dtproj_k(const float* __restrict__ dtw0, const float* __restrict__ xdT0,
              const float* __restrict__ dtw1, const float* __restrict__ xdT1,
              float* __restrict__ SP0, float* __restrict__ SP1)
{
    const int br = blockIdx.z;
    const float* A = br ? dtw1 : dtw0;      // (2048, 64)
    const float* B = br ? xdT1 : xdT0;      // (1024, 96), use cols 0..63
    float* C = br ? SP1 : SP0;

    __shared__ float As[KT][TS + LP];
    __shared__ float Bs[KT][TS + LP];
    const int tid = threadIdx.x;
    const int tx = tid & 15, ty = tid >> 4;
    const int mBase = blockIdx.y * TS;
    const int nBase = blockIdx.x * TS;

    float acc[4][4] = {};
    const int ar = tid >> 2;
    const int ak = (tid & 3) * 4;

    for (int kb = 0; kb < DT_RANK; kb += KT) {
        {
            const float4 av = *(const float4*)&A[(size_t)(mBase + ar) * DT_RANK + kb + ak];
            As[ak + 0][ar] = av.x;
            As[ak + 1][ar] = av.y;
            As[ak + 2][ar] = av.z;
            As[ak + 3][ar] = av.w;
        }
        {
            const float4 bv = *(const float4*)&B[(size_t)(nBase + ar) * 96 + kb + ak];
            Bs[ak + 0][ar] = bv.x;
            Bs[ak + 1][ar] = bv.y;
            Bs[ak + 2][ar] = bv.z;
            Bs[ak + 3][ar] = bv.w;
        }
        __syncthreads();
        #pragma unroll
        for (int k = 0; k < KT; ++k) {
            float4 a = *(const float4*)&As[k][ty * 4];
            float4 b = *(const float4*)&Bs[k][tx * 4];
            float av[4] = {a.x, a.y, a.z, a.w};
            float bv[4] = {b.x, b.y, b.z, b.w};
            #pragma unroll
            for (int i = 0; i < 4; ++i)
                #pragma unroll
                for (int j = 0; j < 4; ++j)
                    acc[i][j] = fmaf(av[i], bv[j], acc[i][j]);
        }
        __syncthreads();
    }

    #pragma unroll
    for (int i = 0; i < 4; ++i)
        #pragma unroll
        for (int j = 0; j < 4; ++j)
            C[(size_t)(mBase + ty * 4 + i) * LSEQ + nBase + tx * 4 + j] = softplus_f(acc[i][j]);
}

// ---------------- depthwise causal conv1d + SiLU ----------------
__global__ __launch_bounds__(256)
void conv_silu_k(const float* __restrict__ xa, const float* __restrict__ x1p,
                 const float* __restrict__ w0, const float* __restrict__ b0,
                 const float* __restrict__ w1, const float* __restrict__ b1,
                 float* __restrict__ co0, float* __restrict__ co1)
{
    const int idx = blockIdx.x * blockDim.x + threadIdx.x;
    const int br  = idx >> 21;
    const int rem = idx & ((1 << 21) - 1);
    const int d = rem >> 10;
    const int l = rem & (LSEQ - 1);

    const float* xin = br ? x1p : xa;
    const float* w   = br ? w1 : w0;
    const float* bb  = br ? b1 : b0;
    float* out       = br ? co1 : co0;

    const float* row = xin + (size_t)d * LSEQ;
    float acc = bb[d];
    #pragma unroll
    for (int j = 0; j < D_CONV; ++j) {
        const int li = l - (D_CONV - 1) + j;
        const float xv = (li >= 0) ? row[li] : 0.f;
        acc = fmaf(w[d * D_CONV + j], xv, acc);
    }
    out[rem] = silu_f(acc);
}

// ---------------- chunk-parallel selective scan (fully de-aliased) ----------------
__global__ __launch_bounds__(256)
void scan5_k(const float* __restrict__ sp0, const float* __restrict__ u0,
             const float* __restrict__ xdT0,
             const float* __restrict__ Al0, const float* __restrict__ Dk0,
             const float* __restrict__ sp1, const float* __restrict__ u1,
             const float* __restrict__ xdT1,
             const float* __restrict__ Al1, const float* __restrict__ Dk1,
             const float* __restrict__ gz,
             float* __restrict__ res0, float* __restrict__ res1)
{
    const int d   = blockIdx.x;
    const int br  = blockIdx.y;
    const int tid = threadIdx.x;
    const int n   = tid & 15;
    const int c   = tid >> 4;

    const float* __restrict__ sp  = br ? sp1  : sp0;
    const float* __restrict__ u   = br ? u1   : u0;
    const float* __restrict__ xdT = br ? xdT1 : xdT0;
    const float* __restrict__ Al  = br ? Al1  : Al0;
    const float* __restrict__ Dk  = br ? Dk1  : Dk0;
    float* __restrict__ res       = br ? res1 : res0;

    const float Adn = -__expf(Al[d * D_STATE + n]);
    const float Dd  = Dk[d];

    const float* __restrict__ srow = sp + (size_t)d * LSEQ;
    const float* __restrict__ urow = u  + (size_t)d * LSEQ;
    const float* __restrict__ grow = gz + (size_t)d * LSEQ;
    const float* __restrict__ bc   = xdT + 64 + 2 * n;
    float* __restrict__ orow = res + (size_t)d * LSEQ;

    const int t0 = c * 64;

    // ---- phase 1: chunk-local (a, b)
    float a = 1.f, b = 0.f;
    for (int tt = 0; tt < 64; tt += 4) {
        const float4 s4 = *(const float4*)&srow[t0 + tt];
        const float4 u4 = *(const float4*)&urow[t0 + tt];
        const float sps[4] = {s4.x, s4.y, s4.z, s4.w};
        const float uvs[4] = {u4.x, u4.y, u4.z, u4.w};
        #pragma unroll
        for (int j = 0; j < 4; ++j) {
            const float2 bcv = *(const float2*)&bc[(size_t)(t0 + tt + j) * 96];
            const float dA = __expf(sps[j] * Adn);
            a *= dA;
            b = fmaf(dA, b, sps[j] * uvs[j] * bcv.x);
        }
    }

    __shared__ float sAm[16][16];
    __shared__ float sBm[16][16];
    __shared__ float sHm[16][16];
    sAm[c][n] = a;
    sBm[c][n] = b;
    __syncthreads();

    // ---- phase 2: serial scan over chunks
    if (tid < 16) {
        float hb = 0.f;
        #pragma unroll
        for (int cc = 0; cc < 16; ++cc) {
            sHm[cc][tid] = hb;
            hb = fmaf(sAm[cc][tid], hb, sBm[cc][tid]);
        }
    }
    __syncthreads();

    // ---- phase 3: re-run chunk from h_start, emit y
    float h = sHm[c][n];
    for (int tt = 0; tt < 64; tt += 4) {
        const float4 s4 = *(const float4*)&srow[t0 + tt];
        const float4 u4 = *(const float4*)&urow[t0 + tt];
        const float4 g4 = *(const float4*)&grow[t0 + tt];
        const float sps[4] = {s4.x, s4.y, s4.z, s4.w};
        const float uvs[4] = {u4.x, u4.y, u4.z, u4.w};
        const float gzs[4] = {g4.x, g4.y, g4.z, g4.w};
        float y4[4];
        #pragma unroll
        for (int j = 0; j < 4; ++j) {
            const float2 bcv = *(const float2*)&bc[(size_t)(t0 + tt + j) * 96];
            const float dA = __expf(sps[j] * Adn);
            h = fmaf(dA, h, sps[j] * uvs[j] * bcv.x);
            float y = h * bcv.y;
            y += __shfl_xor(y, 1);
            y += __shfl_xor(y, 2);
            y += __shfl_xor(y, 4);
            y += __shfl_xor(y, 8);
            y4[j] = y;
        }
        if (n == 0) {
            float4 o;
            float* op = (float*)&o;
            #pragma unroll
            for (int j = 0; j < 4; ++j)
                op[j] = (y4[j] + Dd * uvs[j]) * gzs[j];
            *(float4*)&orow[t0 + tt] = o;
        }
    }
}

// ---------------- launcher ----------------
extern "C" void kernel_launch(void* const* d_in, const int* in_sizes, int n_in,
                              void* d_out, int out_size, void* d_ws, size_t ws_size,
                              hipStream_t stream)
{
    const float* x          = (const float*)d_in[0];
    const float* x1         = (const float*)d_in[1];
    const float* in_proj_w  = (const float*)d_in[2];
    const float* in_proj1_w = (const float*)d_in[3];
    const float* conv_w     = (const float*)d_in[4];
    const float* conv_b     = (const float*)d_in[5];
    const float* conv1_w    = (const float*)d_in[6];
    const float* conv1_b    = (const float*)d_in[7];
    const float* x_proj_w   = (const float*)d_in[8];
    const float* x_proj1_w  = (const float*)d_in[9];
    const float* dt_proj_w  = (const float*)d_in[10];
    const float* dt_proj1_w = (const float*)d_in[11];
    const float* A_log      = (const float*)d_in[12];
    const float* A_log1     = (const float*)d_in[13];
    const float* Dskip      = (const float*)d_in[14];
    const float* Dskip1     = (const float*)d_in[15];
    const float* out_proj_w = (const float*)d_in[16];

    float* ws = (float*)d_ws;
    const size_t CH = (size_t)D_INNER * LSEQ;        // 2 Mi f32
    const size_t XD = (size_t)96 * LSEQ;             // 96 Ki f32
    const size_t F  = 5 * CH + 2 * XD;

    // layout (f32 units), total = 7*CH + 2*XD (~60.75 MB):
    //   [0,CH)        xa (in_proj out, conv input) -> RES0 (scan out)
    //   [CH,2CH)      z -> silu'd in in_proj epilogue (GZ)
    //   [2CH,3CH)     x1p (dead after conv)        -> RES1
    //   [3CH,4CH)     co0
    //   [4CH,5CH)     co1
    //   [5CH,5CH+2XD) xdT0, xdT1
    //   [F,F+2CH)     time-sliced: {WB,XB,WB1,X1B} -> {P0,P1} -> {SP0,SP1} -> {OWB,RESTB}
    float* XA    = ws;
    float* RES0  = ws;                   // over dead xa
    float* GZ    = ws + CH;
    float* X1P   = ws + 2 * CH;
    float* RES1  = ws + 2 * CH;          // over dead x1p
    float* CO0   = ws + 3 * CH;
    float* CO1   = ws + 4 * CH;
    float* XDT0  = ws + 5 * CH;
    float* XDT1  = XDT0 + XD;
    float* XZ    = ws;                   // [0,2CH)

    unsigned short* WB  = (unsigned short*)(ws + F);                       // 4M bf16
    unsigned short* XB  = (unsigned short*)(ws + F + 2 * (CH / 2));       // after 2M f32
    unsigned short* WB1 = (unsigned short*)(ws + F + 5 * (CH / 4) * 2);   // see offsets below
    unsigned short* X1B;
    {
        // recompute cleanly in f32 offsets: WB 2M f32, XB 0.5M, WB1 1M, X1B 0.5M
        WB  = (unsigned short*)(ws + F);
        XB  = (unsigned short*)(ws + F + 2097152);
        WB1 = (unsigned short*)(ws + F + 2097152 + 524288);
        X1B = (unsigned short*)(ws + F + 2097152 + 524288 + 1048576);
    }
    float* P0  = ws + F;                 // 768K f32
    float* P1  = P0 + 8 * XD;
    float* SP0 = ws + F;
    float* SP1 = ws + F + CH;
    unsigned short* OWB   = (unsigned short*)(ws + F);            // 2M bf16 = 1M f32
    unsigned short* RESTB = (unsigned short*)(ws + F + CH / 2);

    float* out = (float*)d_out;

    // 1) convert all four GEMM inputs to bf16 (one launch)
    hipLaunchKernelGGL(cvt_all_k, dim3((2 << 20) / 256), dim3(256), 0, stream,
                       in_proj_w, x, in_proj1_w, x1, WB, XB, WB1, X1B);

    // 2) in_proj + in_proj1 (merged bf16 MFMA); z rows get silu
    hipLaunchKernelGGL(mfma_in_k, dim3(8, 48), dim3(256), 0, stream,
                       WB, XB, WB1, X1B, XZ, X1P);

    // 3) causal conv + silu
    hipLaunchKernelGGL(conv_silu_k, dim3(2 * D_INNER * LSEQ / 256), dim3(256), 0, stream,
                       XA, X1P, conv_w, conv_b, conv1_w, conv1_b, CO0, CO1);

    // 4) x_proj split-K (one launch, 512 blocks)
    hipLaunchKernelGGL(xproj_k, dim3(LSEQ / TS, 2, 16), dim3(256), 0, stream,
                       x_proj_w, CO0, x_proj1_w, CO1, P0, P1);

    // 5) reduce partials -> xdT [L][96] interleaved
    hipLaunchKernelGGL(reduceT_k, dim3(2 * LSEQ * 128 / 256), dim3(256), 0, stream,
                       P0, P1, XDT0, XDT1);

    // 6) dt_proj (both branches) + fused softplus -> SP (overwrites dead P)
    hipLaunchKernelGGL(dtproj_k, dim3(LSEQ / TS, D_INNER / TS, 2), dim3(256), 0, stream,
                       dt_proj_w, XDT0, dt_proj1_w, XDT1, SP0, SP1);

    // 7) chunk-parallel scan -> RES (de-aliased, all restrict)
    hipLaunchKernelGGL(scan5_k, dim3(D_INNER, 2), dim3(256), 0, stream,
                       SP0, CO0, XDT0, A_log, Dskip,
                       SP1, CO1, XDT1, A_log1, Dskip1,
                       GZ, RES0, RES1);

    // 8) OWB = bf16(out_proj_w); REST[l,d] = bf16(res0+res1)
    hipLaunchKernelGGL(cvt_k, dim3((1024 * 2048 / 4) / 256), dim3(256), 0, stream,
                       out_proj_w, OWB, 1024 * 2048 / 4);
    hipLaunchKernelGGL(cvtT_add_k, dim3(LSEQ / 32, D_INNER / 32), dim3(256), 0, stream,
                       RES0, RES1, RESTB);

    // 9) out_proj (bf16 MFMA)
    hipLaunchKernelGGL(mfma_out_k, dim3(8, 8), dim3(256), 0, stream,
                       RESTB, OWB, out);
}

// Round 7
// 241.263 us; speedup vs baseline: 9.6116x; 1.0518x over previous
//
#include <hip/hip_runtime.h>
#include <hip/hip_bf16.h>
#include <math.h>

// ---------------- problem constants ----------------
#define D_MODEL 1024
#define D_STATE 16
#define D_CONV  4
#define D_INNER 2048
#define DT_RANK 64
#define LSEQ    1024

typedef short bf16x8 __attribute__((ext_vector_type(8)));
typedef float f32x4  __attribute__((ext_vector_type(4)));

__device__ __forceinline__ float softplus_f(float x) {
    const float sp = __logf(1.f + __expf(x));
    return (x > 20.f) ? x : sp;
}
__device__ __forceinline__ float silu_f(float x) {
    return x / (1.f + __expf(-x));
}
__device__ __forceinline__ unsigned short f2bf(float f) {
    union { float f; unsigned int u; } c; c.f = f;
    const unsigned int u = c.u;
    return (unsigned short)((u + 0x7FFFu + ((u >> 16) & 1u)) >> 16);
}

// ---------------- fused fp32->bf16 convert of all 4 GEMM inputs ----------------
__global__ __launch_bounds__(256)
void cvt_all_k(const float* __restrict__ w0, const float* __restrict__ xx,
               const float* __restrict__ w1, const float* __restrict__ xx1,
               unsigned short* __restrict__ WB, unsigned short* __restrict__ XB,
               unsigned short* __restrict__ WB1, unsigned short* __restrict__ X1B)
{
    const int i = blockIdx.x * 256 + threadIdx.x;
    const float* src; unsigned short* dst; int j;
    if (i < (1 << 20))            { src = w0;  dst = WB;  j = i; }
    else if (i < (5 << 18))       { src = xx;  dst = XB;  j = i - (1 << 20); }
    else if (i < (7 << 18))       { src = w1;  dst = WB1; j = i - (5 << 18); }
    else                          { src = xx1; dst = X1B; j = i - (7 << 18); }
    const float4 v = *(const float4*)&src[(size_t)j * 4];
    ushort4 o;
    o.x = f2bf(v.x); o.y = f2bf(v.y); o.z = f2bf(v.z); o.w = f2bf(v.w);
    *(ushort4*)&dst[(size_t)j * 4] = o;
}

__global__ __launch_bounds__(256)
void cvt_k(const float* __restrict__ in, unsigned short* __restrict__ out, int n4)
{
    const int i = blockIdx.x * 256 + threadIdx.x;
    if (i >= n4) return;
    const float4 v = *(const float4*)&in[(size_t)i * 4];
    ushort4 o;
    o.x = f2bf(v.x); o.y = f2bf(v.y); o.z = f2bf(v.z); o.w = f2bf(v.w);
    *(ushort4*)&out[(size_t)i * 4] = o;
}

// ---------------- transpose + add + convert: REST[l][d] = bf16(res0[d][l]+res1[d][l]) ----
__global__ __launch_bounds__(256)
void cvtT_add_k(const float* __restrict__ r0, const float* __restrict__ r1,
                unsigned short* __restrict__ dst)
{
    __shared__ float s[32][33];
    const int tx = threadIdx.x & 31, ty = threadIdx.x >> 5;
    const int dBase = blockIdx.y * 32, lBase = blockIdx.x * 32;
    #pragma unroll
    for (int i = 0; i < 4; ++i) {
        const int d = dBase + ty + i * 8;
        const size_t off = (size_t)d * LSEQ + lBase + tx;
        s[ty + i * 8][tx] = r0[off] + r1[off];
    }
    __syncthreads();
    #pragma unroll
    for (int i = 0; i < 4; ++i) {
        const int l = lBase + ty + i * 8;
        dst[(size_t)l * D_INNER + dBase + tx] = f2bf(s[tx][ty + i * 8]);
    }
}

// ---------------- bf16 MFMA GEMM core (NT), 128x128 tile, 4 waves ----------------
__device__ __forceinline__
void mfma_tile(const unsigned short* __restrict__ A, const unsigned short* __restrict__ B,
               float* __restrict__ C, int N, int K, int mBase, int nBase, int siluRow)
{
    __shared__ unsigned short As[128][40];
    __shared__ unsigned short Bs[128][40];
    const int tid = threadIdx.x;
    const int lane = tid & 63, w = tid >> 6;
    const int wr = w >> 1, wc = w & 1;
    const int l15 = lane & 15, l4 = lane >> 4;

    f32x4 acc[4][4] = {};
    const int sr = tid >> 2;
    const int sk = (tid & 3) * 8;

    for (int kb = 0; kb < K; kb += 32) {
        #pragma unroll
        for (int it = 0; it < 2; ++it) {
            const int r = it * 64 + sr;
            const float4 va = *(const float4*)&A[(size_t)(mBase + r) * K + kb + sk];
            *(float4*)&As[r][sk] = va;
            const float4 vb = *(const float4*)&B[(size_t)(nBase + r) * K + kb + sk];
            *(float4*)&Bs[r][sk] = vb;
        }
        __syncthreads();
        bf16x8 af[4], bfr[4];
        #pragma unroll
        for (int i = 0; i < 4; ++i) {
            af[i]  = *(const bf16x8*)&As[wr * 64 + i * 16 + l15][l4 * 8];
            bfr[i] = *(const bf16x8*)&Bs[wc * 64 + i * 16 + l15][l4 * 8];
        }
        #pragma unroll
        for (int i = 0; i < 4; ++i)
            #pragma unroll
            for (int j = 0; j < 4; ++j)
                acc[i][j] = __builtin_amdgcn_mfma_f32_16x16x32_bf16(af[i], bfr[j], acc[i][j], 0, 0, 0);
        __syncthreads();
    }

    #pragma unroll
    for (int i = 0; i < 4; ++i) {
        const int row0 = mBase + wr * 64 + i * 16 + l4 * 4;
        #pragma unroll
        for (int j = 0; j < 4; ++j) {
            const int col = nBase + wc * 64 + j * 16 + l15;
            #pragma unroll
            for (int r = 0; r < 4; ++r) {
                float v = acc[i][j][r];
                if (row0 + r >= siluRow) v = silu_f(v);
                C[(size_t)(row0 + r) * N + col] = v;
            }
        }
    }
}

__global__ __launch_bounds__(256)
void mfma_in_k(const unsigned short* __restrict__ WB, const unsigned short* __restrict__ XB,
               const unsigned short* __restrict__ WB1, const unsigned short* __restrict__ X1B,
               float* __restrict__ XZ, float* __restrict__ X1P)
{
    const int by = blockIdx.y;
    if (by < 32)
        mfma_tile(WB, XB, XZ, 1024, 1024, by * 128, blockIdx.x * 128, 2048);
    else
        mfma_tile(WB1, X1B, X1P, 1024, 1024, (by - 32) * 128, blockIdx.x * 128, 1 << 30);
}

__global__ __launch_bounds__(256)
void mfma_out_k(const unsigned short* __restrict__ RESTB, const unsigned short* __restrict__ OWB,
                float* __restrict__ C)
{
    mfma_tile(RESTB, OWB, C, 1024, 2048, blockIdx.y * 128, blockIdx.x * 128, 1 << 30);
}

// ---------------- x_proj split-K, single launch ----------------
constexpr int TS = 64;
constexpr int KT = 16;
constexpr int LP = 4;

__global__ __launch_bounds__(256)
void xproj_k(const float* __restrict__ xw0, const float* __restrict__ co0,
             const float* __restrict__ xw1, const float* __restrict__ co1,
             float* __restrict__ P0, float* __restrict__ P1)
{
    const int br = blockIdx.z >> 3;
    const int sl = blockIdx.z & 7;
    const float* A = (br ? xw1 : xw0) + sl * 256;
    const float* B = (br ? co1 : co0) + (size_t)sl * 256 * LSEQ;
    float* C = (br ? P1 : P0) + (size_t)sl * 96 * LSEQ;

    __shared__ float As[KT][TS + LP];
    __shared__ float Bs[KT][TS + LP];
    const int tid = threadIdx.x;
    const int tx = tid & 15, ty = tid >> 4;
    const int mBase = blockIdx.y * TS;
    const int nBase = blockIdx.x * TS;

    float acc[4][4] = {};
    const int ar = tid >> 2;
    const int ak = (tid & 3) * 4;

    for (int kb = 0; kb < 256; kb += KT) {
        {
            const int gm = mBase + ar;
            float4 av = make_float4(0.f, 0.f, 0.f, 0.f);
            if (gm < 96) av = *(const float4*)&A[(size_t)gm * D_INNER + kb + ak];
            As[ak + 0][ar] = av.x;
            As[ak + 1][ar] = av.y;
            As[ak + 2][ar] = av.z;
            As[ak + 3][ar] = av.w;
        }
        {
            const int bk = tid >> 4;
            const int bn = (tid & 15) * 4;
            const float4 bv = *(const float4*)&B[(size_t)(kb + bk) * LSEQ + nBase + bn];
            *(float4*)&Bs[bk][bn] = bv;
        }
        __syncthreads();
        #pragma unroll
        for (int k = 0; k < KT; ++k) {
            float4 a = *(const float4*)&As[k][ty * 4];
            float4 b = *(const float4*)&Bs[k][tx * 4];
            float av[4] = {a.x, a.y, a.z, a.w};
            float bv[4] = {b.x, b.y, b.z, b.w};
            #pragma unroll
            for (int i = 0; i < 4; ++i)
                #pragma unroll
                for (int j = 0; j < 4; ++j)
                    acc[i][j] = fmaf(av[i], bv[j], acc[i][j]);
        }
        __syncthreads();
    }

    #pragma unroll
    for (int i = 0; i < 4; ++i) {
        const int m = mBase + ty * 4 + i;
        if (m >= 96) continue;
        #pragma unroll
        for (int j = 0; j < 4; ++j)
            C[(size_t)m * LSEQ + nBase + tx * 4 + j] = acc[i][j];
    }
}

// ---------------- reduce split-K partials + transpose + interleave B/C ----------------
__global__ __launch_bounds__(256)
void reduceT_k(const float* __restrict__ P0, const float* __restrict__ P1,
               float* __restrict__ xdT0, float* __restrict__ xdT1)
{
    const int idx = blockIdx.x * 256 + threadIdx.x;
    const int k = idx & 127;
    const int l = (idx >> 7) & (LSEQ - 1);
    const int br = idx >> 17;
    if (k >= 96) return;
    const int srck = (k < 64) ? k : (64 + ((k - 64) >> 1) + ((k & 1) << 4));
    const float* P = br ? P1 : P0;
    float s = 0.f;
    #pragma unroll
    for (int sl = 0; sl < 8; ++sl)
        s += P[(size_t)sl * 96 * LSEQ + (size_t)srck * LSEQ + l];
    float* o = br ? xdT1 : xdT0;
    o[(size_t)l * 96 + k] = s;
}

// ---------------- dt_proj (both branches) + fused softplus ----------------
__global__ __launch_bounds__(256)
void dtproj_k(const float* __restrict__ dtw0, const float* __restrict__ xdT0,
              const float* __restrict__ dtw1, const float* __restrict__ xdT1,
              float* __restrict__ SP0, float* __restrict__ SP1)
{
    const int br = blockIdx.z;
    const float* A = br ? dtw1 : dtw0;
    const float* B = br ? xdT1 : xdT0;
    float* C = br ? SP1 : SP0;

    __shared__ float As[KT][TS + LP];
    __shared__ float Bs[KT][TS + LP];
    const int tid = threadIdx.x;
    const int tx = tid & 15, ty = tid >> 4;
    const int mBase = blockIdx.y * TS;
    const int nBase = blockIdx.x * TS;

    float acc[4][4] = {};
    const int ar = tid >> 2;
    const int ak = (tid & 3) * 4;

    for (int kb = 0; kb < DT_RANK; kb += KT) {
        {
            const float4 av = *(const float4*)&A[(size_t)(mBase + ar) * DT_RANK + kb + ak];
            As[ak + 0][ar] = av.x;
            As[ak + 1][ar] = av.y;
            As[ak + 2][ar] = av.z;
            As[ak + 3][ar] = av.w;
        }
        {
            const float4 bv = *(const float4*)&B[(size_t)(nBase + ar) * 96 + kb + ak];
            Bs[ak + 0][ar] = bv.x;
            Bs[ak + 1][ar] = bv.y;
            Bs[ak + 2][ar] = bv.z;
            Bs[ak + 3][ar] = bv.w;
        }
        __syncthreads();
        #pragma unroll
        for (int k = 0; k < KT; ++k) {
            float4 a = *(const float4*)&As[k][ty * 4];
            float4 b = *(const float4*)&Bs[k][tx * 4];
            float av[4] = {a.x, a.y, a.z, a.w};
            float bv[4] = {b.x, b.y, b.z, b.w};
            #pragma unroll
            for (int i = 0; i < 4; ++i)
                #pragma unroll
                for (int j = 0; j < 4; ++j)
                    acc[i][j] = fmaf(av[i], bv[j], acc[i][j]);
        }
        __syncthreads();
    }

    #pragma unroll
    for (int i = 0; i < 4; ++i)
        #pragma unroll
        for (int j = 0; j < 4; ++j)
            C[(size_t)(mBase + ty * 4 + i) * LSEQ + nBase + tx * 4 + j] = softplus_f(acc[i][j]);
}

// ---------------- depthwise causal conv1d + SiLU ----------------
__global__ __launch_bounds__(256)
void conv_silu_k(const float* __restrict__ xa, const float* __restrict__ x1p,
                 const float* __restrict__ w0, const float* __restrict__ b0,
                 const float* __restrict__ w1, const float* __restrict__ b1,
                 float* __restrict__ co0, float* __restrict__ co1)
{
    const int idx = blockIdx.x * blockDim.x + threadIdx.x;
    const int br  = idx >> 21;
    const int rem = idx & ((1 << 21) - 1);
    const int d = rem >> 10;
    const int l = rem & (LSEQ - 1);

    const float* xin = br ? x1p : xa;
    const float* w   = br ? w1 : w0;
    const float* bb  = br ? b1 : b0;
    float* out       = br ? co1 : co0;

    const float* row = xin + (size_t)d * LSEQ;
    float acc = bb[d];
    #pragma unroll
    for (int j = 0; j < D_CONV; ++j) {
        const int li = l - (D_CONV - 1) + j;
        const float xv = (li >= 0) ? row[li] : 0.f;
        acc = fmaf(w[d * D_CONV + j], xv, acc);
    }
    out[rem] = silu_f(acc);
}

// ---------------- chunk-parallel selective scan, 4 channels/block (ILP x4) ----------------
// grid (D_INNER/4, 2). 256 threads = 16 chunks x 16 states; each thread runs 4
// independent channel chains; bc (B/C) loads shared across the 4 channels.
__global__ __launch_bounds__(256)
void scan6_k(const float* __restrict__ sp0, const float* __restrict__ u0,
             const float* __restrict__ xdT0,
             const float* __restrict__ Al0, const float* __restrict__ Dk0,
             const float* __restrict__ sp1, const float* __restrict__ u1,
             const float* __restrict__ xdT1,
             const float* __restrict__ Al1, const float* __restrict__ Dk1,
             const float* __restrict__ gz,
             float* __restrict__ res0, float* __restrict__ res1)
{
    const int d0  = blockIdx.x * 4;
    const int br  = blockIdx.y;
    const int tid = threadIdx.x;
    const int n   = tid & 15;
    const int c   = tid >> 4;

    const float* __restrict__ sp  = br ? sp1  : sp0;
    const float* __restrict__ u   = br ? u1   : u0;
    const float* __restrict__ xdT = br ? xdT1 : xdT0;
    const float* __restrict__ Al  = br ? Al1  : Al0;
    const float* __restrict__ Dk  = br ? Dk1  : Dk0;
    float* __restrict__ res       = br ? res1 : res0;

    float Adn[4], Dd[4];
    const float* srow[4]; const float* urow[4]; const float* grow[4]; float* orow[4];
    #pragma unroll
    for (int g = 0; g < 4; ++g) {
        Adn[g] = -__expf(Al[(d0 + g) * D_STATE + n]);
        Dd[g]  = Dk[d0 + g];
        srow[g] = sp + (size_t)(d0 + g) * LSEQ;
        urow[g] = u  + (size_t)(d0 + g) * LSEQ;
        grow[g] = gz + (size_t)(d0 + g) * LSEQ;
        orow[g] = res + (size_t)(d0 + g) * LSEQ;
    }
    const float* __restrict__ bc = xdT + 64 + 2 * n;
    const int t0 = c * 64;

    // ---- phase 1: chunk-local (a, b) per channel
    float a[4] = {1.f, 1.f, 1.f, 1.f};
    float b[4] = {0.f, 0.f, 0.f, 0.f};
    for (int tt = 0; tt < 64; tt += 4) {
        float2 bcv[4];
        #pragma unroll
        for (int j = 0; j < 4; ++j)
            bcv[j] = *(const float2*)&bc[(size_t)(t0 + tt + j) * 96];
        #pragma unroll
        for (int g = 0; g < 4; ++g) {
            const float4 s4 = *(const float4*)&srow[g][t0 + tt];
            const float4 u4 = *(const float4*)&urow[g][t0 + tt];
            const float sps[4] = {s4.x, s4.y, s4.z, s4.w};
            const float uvs[4] = {u4.x, u4.y, u4.z, u4.w};
            #pragma unroll
            for (int j = 0; j < 4; ++j) {
                const float dA = __expf(sps[j] * Adn[g]);
                a[g] *= dA;
                b[g] = fmaf(dA, b[g], sps[j] * uvs[j] * bcv[j].x);
            }
        }
    }

    __shared__ float sAm[16][16][4];
    __shared__ float sBm[16][16][4];
    __shared__ float sHm[16][16][4];
    #pragma unroll
    for (int g = 0; g < 4; ++g) { sAm[c][n][g] = a[g]; sBm[c][n][g] = b[g]; }
    __syncthreads();

    // ---- phase 2: serial scan over chunks (64 threads: one per (n, g))
    if (tid < 64) {
        const int n2 = tid & 15, g2 = tid >> 4;
        float hb = 0.f;
        #pragma unroll
        for (int cc = 0; cc < 16; ++cc) {
            sHm[cc][n2][g2] = hb;
            hb = fmaf(sAm[cc][n2][g2], hb, sBm[cc][n2][g2]);
        }
    }
    __syncthreads();

    // ---- phase 3: re-run chunk from h_start, emit y
    float h[4];
    #pragma unroll
    for (int g = 0; g < 4; ++g) h[g] = sHm[c][n][g];

    for (int tt = 0; tt < 64; tt += 4) {
        float2 bcv[4];
        #pragma unroll
        for (int j = 0; j < 4; ++j)
            bcv[j] = *(const float2*)&bc[(size_t)(t0 + tt + j) * 96];
        #pragma unroll
        for (int g = 0; g < 4; ++g) {
            const float4 s4 = *(const float4*)&srow[g][t0 + tt];
            const float4 u4 = *(const float4*)&urow[g][t0 + tt];
            const float4 g4 = *(const float4*)&grow[g][t0 + tt];
            const float sps[4] = {s4.x, s4.y, s4.z, s4.w};
            const float uvs[4] = {u4.x, u4.y, u4.z, u4.w};
            const float gzs[4] = {g4.x, g4.y, g4.z, g4.w};
            float y4[4];
            #pragma unroll
            for (int j = 0; j < 4; ++j) {
                const float dA = __expf(sps[j] * Adn[g]);
                h[g] = fmaf(dA, h[g], sps[j] * uvs[j] * bcv[j].x);
                float y = h[g] * bcv[j].y;
                y += __shfl_xor(y, 1);
                y += __shfl_xor(y, 2);
                y += __shfl_xor(y, 4);
                y += __shfl_xor(y, 8);
                y4[j] = y;
            }
            if (n == 0) {
                float4 o;
                float* op = (float*)&o;
                #pragma unroll
                for (int j = 0; j < 4; ++j)
                    op[j] = (y4[j] + Dd[g] * uvs[j]) * gzs[j];
                *(float4*)&orow[g][t0 + tt] = o;
            }
        }
    }
}

// ---------------- launcher ----------------
extern "C" void kernel_launch(void* const* d_in, const int* in_sizes, int n_in,
                              void* d_out, int out_size, void* d_ws, size_t ws_size,
                              hipStream_t stream)
{
    const float* x          = (const float*)d_in[0];
    const float* x1         = (const float*)d_in[1];
    const float* in_proj_w  = (const float*)d_in[2];
    const float* in_proj1_w = (const float*)d_in[3];
    const float* conv_w     = (const float*)d_in[4];
    const float* conv_b     = (const float*)d_in[5];
    const float* conv1_w    = (const float*)d_in[6];
    const float* conv1_b    = (const float*)d_in[7];
    const float* x_proj_w   = (const float*)d_in[8];
    const float* x_proj1_w  = (const float*)d_in[9];
    const float* dt_proj_w  = (const float*)d_in[10];
    const float* dt_proj1_w = (const float*)d_in[11];
    const float* A_log      = (const float*)d_in[12];
    const float* A_log1     = (const float*)d_in[13];
    const float* Dskip      = (const float*)d_in[14];
    const float* Dskip1     = (const float*)d_in[15];
    const float* out_proj_w = (const float*)d_in[16];

    float* ws = (float*)d_ws;
    const size_t CH = (size_t)D_INNER * LSEQ;
    const size_t XD = (size_t)96 * LSEQ;
    const size_t F  = 5 * CH + 2 * XD;

    float* XA    = ws;
    float* RES0  = ws;                   // over dead xa
    float* GZ    = ws + CH;
    float* X1P   = ws + 2 * CH;
    float* RES1  = ws + 2 * CH;          // over dead x1p
    float* CO0   = ws + 3 * CH;
    float* CO1   = ws + 4 * CH;
    float* XDT0  = ws + 5 * CH;
    float* XDT1  = XDT0 + XD;
    float* XZ    = ws;

    unsigned short* WB  = (unsigned short*)(ws + F);
    unsigned short* XB  = (unsigned short*)(ws + F + 2097152);
    unsigned short* WB1 = (unsigned short*)(ws + F + 2097152 + 524288);
    unsigned short* X1B = (unsigned short*)(ws + F + 2097152 + 524288 + 1048576);
    float* P0  = ws + F;
    float* P1  = P0 + 8 * XD;
    float* SP0 = ws + F;
    float* SP1 = ws + F + CH;
    unsigned short* OWB   = (unsigned short*)(ws + F);
    unsigned short* RESTB = (unsigned short*)(ws + F + CH / 2);

    float* out = (float*)d_out;

    // 1) convert all four GEMM inputs to bf16
    hipLaunchKernelGGL(cvt_all_k, dim3((2 << 20) / 256), dim3(256), 0, stream,
                       in_proj_w, x, in_proj1_w, x1, WB, XB, WB1, X1B);

    // 2) in_proj + in_proj1 (merged bf16 MFMA); z rows get silu
    hipLaunchKernelGGL(mfma_in_k, dim3(8, 48), dim3(256), 0, stream,
                       WB, XB, WB1, X1B, XZ, X1P);

    // 3) causal conv + silu
    hipLaunchKernelGGL(conv_silu_k, dim3(2 * D_INNER * LSEQ / 256), dim3(256), 0, stream,
                       XA, X1P, conv_w, conv_b, conv1_w, conv1_b, CO0, CO1);

    // 4) x_proj split-K (one launch, 512 blocks)
    hipLaunchKernelGGL(xproj_k, dim3(LSEQ / TS, 2, 16), dim3(256), 0, stream,
                       x_proj_w, CO0, x_proj1_w, CO1, P0, P1);

    // 5) reduce partials -> xdT [L][96] interleaved
    hipLaunchKernelGGL(reduceT_k, dim3(2 * LSEQ * 128 / 256), dim3(256), 0, stream,
                       P0, P1, XDT0, XDT1);

    // 6) dt_proj (both branches) + fused softplus -> SP
    hipLaunchKernelGGL(dtproj_k, dim3(LSEQ / TS, D_INNER / TS, 2), dim3(256), 0, stream,
                       dt_proj_w, XDT0, dt_proj1_w, XDT1, SP0, SP1);

    // 7) chunk-parallel scan, 4 channels/block
    hipLaunchKernelGGL(scan6_k, dim3(D_INNER / 4, 2), dim3(256), 0, stream,
                       SP0, CO0, XDT0, A_log, Dskip,
                       SP1, CO1, XDT1, A_log1, Dskip1,
                       GZ, RES0, RES1);

    // 8) OWB = bf16(out_proj_w); REST[l,d] = bf16(res0+res1)
    hipLaunchKernelGGL(cvt_k, dim3((1024 * 2048 / 4) / 256), dim3(256), 0, stream,
                       out_proj_w, OWB, 1024 * 2048 / 4);
    hipLaunchKernelGGL(cvtT_add_k, dim3(LSEQ / 32, D_INNER / 32), dim3(256), 0, stream,
                       RES0, RES1, RESTB);

    // 9) out_proj (bf16 MFMA)
    hipLaunchKernelGGL(mfma_out_k, dim3(8, 8), dim3(256), 0, stream,
                       RESTB, OWB, out);
}

// Round 8
// 236.614 us; speedup vs baseline: 9.8005x; 1.0196x over previous
//
#include <hip/hip_runtime.h>
#include <hip/hip_bf16.h>
#include <math.h>

// ---------------- problem constants ----------------
#define D_MODEL 1024
#define D_STATE 16
#define D_CONV  4
#define D_INNER 2048
#define DT_RANK 64
#define LSEQ    1024

typedef short bf16x8 __attribute__((ext_vector_type(8)));
typedef float f32x4  __attribute__((ext_vector_type(4)));

__device__ __forceinline__ float softplus_f(float x) {
    const float sp = __logf(1.f + __expf(x));
    return (x > 20.f) ? x : sp;
}
__device__ __forceinline__ float silu_f(float x) {
    return x / (1.f + __expf(-x));
}
__device__ __forceinline__ unsigned short f2bf(float f) {
    union { float f; unsigned int u; } c; c.f = f;
    const unsigned int u = c.u;
    return (unsigned short)((u + 0x7FFFu + ((u >> 16) & 1u)) >> 16);
}

// ---------------- fused fp32->bf16 convert of all 4 GEMM inputs ----------------
__global__ __launch_bounds__(256)
void cvt_all_k(const float* __restrict__ w0, const float* __restrict__ xx,
               const float* __restrict__ w1, const float* __restrict__ xx1,
               unsigned short* __restrict__ WB, unsigned short* __restrict__ XB,
               unsigned short* __restrict__ WB1, unsigned short* __restrict__ X1B)
{
    const int i = blockIdx.x * 256 + threadIdx.x;
    const float* src; unsigned short* dst; int j;
    if (i < (1 << 20))            { src = w0;  dst = WB;  j = i; }
    else if (i < (5 << 18))       { src = xx;  dst = XB;  j = i - (1 << 20); }
    else if (i < (7 << 18))       { src = w1;  dst = WB1; j = i - (5 << 18); }
    else                          { src = xx1; dst = X1B; j = i - (7 << 18); }
    const float4 v = *(const float4*)&src[(size_t)j * 4];
    ushort4 o;
    o.x = f2bf(v.x); o.y = f2bf(v.y); o.z = f2bf(v.z); o.w = f2bf(v.w);
    *(ushort4*)&dst[(size_t)j * 4] = o;
}

__global__ __launch_bounds__(256)
void cvt_k(const float* __restrict__ in, unsigned short* __restrict__ out, int n4)
{
    const int i = blockIdx.x * 256 + threadIdx.x;
    if (i >= n4) return;
    const float4 v = *(const float4*)&in[(size_t)i * 4];
    ushort4 o;
    o.x = f2bf(v.x); o.y = f2bf(v.y); o.z = f2bf(v.z); o.w = f2bf(v.w);
    *(ushort4*)&out[(size_t)i * 4] = o;
}

// ---------------- transpose + add + convert: REST[l][d] = bf16(res0[d][l]+res1[d][l]) ----
__global__ __launch_bounds__(256)
void cvtT_add_k(const float* __restrict__ r0, const float* __restrict__ r1,
                unsigned short* __restrict__ dst)
{
    __shared__ float s[32][33];
    const int tx = threadIdx.x & 31, ty = threadIdx.x >> 5;
    const int dBase = blockIdx.y * 32, lBase = blockIdx.x * 32;
    #pragma unroll
    for (int i = 0; i < 4; ++i) {
        const int d = dBase + ty + i * 8;
        const size_t off = (size_t)d * LSEQ + lBase + tx;
        s[ty + i * 8][tx] = r0[off] + r1[off];
    }
    __syncthreads();
    #pragma unroll
    for (int i = 0; i < 4; ++i) {
        const int l = lBase + ty + i * 8;
        dst[(size_t)l * D_INNER + dBase + tx] = f2bf(s[tx][ty + i * 8]);
    }
}

// ---------------- bf16 MFMA GEMM core (NT), 128x128 tile, 4 waves ----------------
__device__ __forceinline__
void mfma_tile(const unsigned short* __restrict__ A, const unsigned short* __restrict__ B,
               float* __restrict__ C, int N, int K, int mBase, int nBase, int siluRow)
{
    __shared__ unsigned short As[128][40];
    __shared__ unsigned short Bs[128][40];
    const int tid = threadIdx.x;
    const int lane = tid & 63, w = tid >> 6;
    const int wr = w >> 1, wc = w & 1;
    const int l15 = lane & 15, l4 = lane >> 4;

    f32x4 acc[4][4] = {};
    const int sr = tid >> 2;
    const int sk = (tid & 3) * 8;

    for (int kb = 0; kb < K; kb += 32) {
        #pragma unroll
        for (int it = 0; it < 2; ++it) {
            const int r = it * 64 + sr;
            const float4 va = *(const float4*)&A[(size_t)(mBase + r) * K + kb + sk];
            *(float4*)&As[r][sk] = va;
            const float4 vb = *(const float4*)&B[(size_t)(nBase + r) * K + kb + sk];
            *(float4*)&Bs[r][sk] = vb;
        }
        __syncthreads();
        bf16x8 af[4], bfr[4];
        #pragma unroll
        for (int i = 0; i < 4; ++i) {
            af[i]  = *(const bf16x8*)&As[wr * 64 + i * 16 + l15][l4 * 8];
            bfr[i] = *(const bf16x8*)&Bs[wc * 64 + i * 16 + l15][l4 * 8];
        }
        #pragma unroll
        for (int i = 0; i < 4; ++i)
            #pragma unroll
            for (int j = 0; j < 4; ++j)
                acc[i][j] = __builtin_amdgcn_mfma_f32_16x16x32_bf16(af[i], bfr[j], acc[i][j], 0, 0, 0);
        __syncthreads();
    }

    #pragma unroll
    for (int i = 0; i < 4; ++i) {
        const int row0 = mBase + wr * 64 + i * 16 + l4 * 4;
        #pragma unroll
        for (int j = 0; j < 4; ++j) {
            const int col = nBase + wc * 64 + j * 16 + l15;
            #pragma unroll
            for (int r = 0; r < 4; ++r) {
                float v = acc[i][j][r];
                if (row0 + r >= siluRow) v = silu_f(v);
                C[(size_t)(row0 + r) * N + col] = v;
            }
        }
    }
}

__global__ __launch_bounds__(256)
void mfma_in_k(const unsigned short* __restrict__ WB, const unsigned short* __restrict__ XB,
               const unsigned short* __restrict__ WB1, const unsigned short* __restrict__ X1B,
               float* __restrict__ XZ, float* __restrict__ X1P)
{
    const int by = blockIdx.y;
    if (by < 32)
        mfma_tile(WB, XB, XZ, 1024, 1024, by * 128, blockIdx.x * 128, 2048);
    else
        mfma_tile(WB1, X1B, X1P, 1024, 1024, (by - 32) * 128, blockIdx.x * 128, 1 << 30);
}

__global__ __launch_bounds__(256)
void mfma_out_k(const unsigned short* __restrict__ RESTB, const unsigned short* __restrict__ OWB,
                float* __restrict__ C)
{
    mfma_tile(RESTB, OWB, C, 1024, 2048, blockIdx.y * 128, blockIdx.x * 128, 1 << 30);
}

// ---------------- x_proj split-K, single launch ----------------
constexpr int TS = 64;
constexpr int KT = 16;
constexpr int LP = 4;

__global__ __launch_bounds__(256)
void xproj_k(const float* __restrict__ xw0, const float* __restrict__ co0,
             const float* __restrict__ xw1, const float* __restrict__ co1,
             float* __restrict__ P0, float* __restrict__ P1)
{
    const int br = blockIdx.z >> 3;
    const int sl = blockIdx.z & 7;
    const float* A = (br ? xw1 : xw0) + sl * 256;
    const float* B = (br ? co1 : co0) + (size_t)sl * 256 * LSEQ;
    float* C = (br ? P1 : P0) + (size_t)sl * 96 * LSEQ;

    __shared__ float As[KT][TS + LP];
    __shared__ float Bs[KT][TS + LP];
    const int tid = threadIdx.x;
    const int tx = tid & 15, ty = tid >> 4;
    const int mBase = blockIdx.y * TS;
    const int nBase = blockIdx.x * TS;

    float acc[4][4] = {};
    const int ar = tid >> 2;
    const int ak = (tid & 3) * 4;

    for (int kb = 0; kb < 256; kb += KT) {
        {
            const int gm = mBase + ar;
            float4 av = make_float4(0.f, 0.f, 0.f, 0.f);
            if (gm < 96) av = *(const float4*)&A[(size_t)gm * D_INNER + kb + ak];
            As[ak + 0][ar] = av.x;
            As[ak + 1][ar] = av.y;
            As[ak + 2][ar] = av.z;
            As[ak + 3][ar] = av.w;
        }
        {
            const int bk = tid >> 4;
            const int bn = (tid & 15) * 4;
            const float4 bv = *(const float4*)&B[(size_t)(kb + bk) * LSEQ + nBase + bn];
            *(float4*)&Bs[bk][bn] = bv;
        }
        __syncthreads();
        #pragma unroll
        for (int k = 0; k < KT; ++k) {
            float4 a = *(const float4*)&As[k][ty * 4];
            float4 b = *(const float4*)&Bs[k][tx * 4];
            float av[4] = {a.x, a.y, a.z, a.w};
            float bv[4] = {b.x, b.y, b.z, b.w};
            #pragma unroll
            for (int i = 0; i < 4; ++i)
                #pragma unroll
                for (int j = 0; j < 4; ++j)
                    acc[i][j] = fmaf(av[i], bv[j], acc[i][j]);
        }
        __syncthreads();
    }

    #pragma unroll
    for (int i = 0; i < 4; ++i) {
        const int m = mBase + ty * 4 + i;
        if (m >= 96) continue;
        #pragma unroll
        for (int j = 0; j < 4; ++j)
            C[(size_t)m * LSEQ + nBase + tx * 4 + j] = acc[i][j];
    }
}

// ---------------- reduce split-K partials + transpose + interleave B/C ----------------
__global__ __launch_bounds__(256)
void reduceT_k(const float* __restrict__ P0, const float* __restrict__ P1,
               float* __restrict__ xdT0, float* __restrict__ xdT1)
{
    const int idx = blockIdx.x * 256 + threadIdx.x;
    const int k = idx & 127;
    const int l = (idx >> 7) & (LSEQ - 1);
    const int br = idx >> 17;
    if (k >= 96) return;
    const int srck = (k < 64) ? k : (64 + ((k - 64) >> 1) + ((k & 1) << 4));
    const float* P = br ? P1 : P0;
    float s = 0.f;
    #pragma unroll
    for (int sl = 0; sl < 8; ++sl)
        s += P[(size_t)sl * 96 * LSEQ + (size_t)srck * LSEQ + l];
    float* o = br ? xdT1 : xdT0;
    o[(size_t)l * 96 + k] = s;
}

// ---------------- dt_proj (both branches) + fused softplus ----------------
__global__ __launch_bounds__(256)
void dtproj_k(const float* __restrict__ dtw0, const float* __restrict__ xdT0,
              const float* __restrict__ dtw1, const float* __restrict__ xdT1,
              float* __restrict__ SP0, float* __restrict__ SP1)
{
    const int br = blockIdx.z;
    const float* A = br ? dtw1 : dtw0;
    const float* B = br ? xdT1 : xdT0;
    float* C = br ? SP1 : SP0;

    __shared__ float As[KT][TS + LP];
    __shared__ float Bs[KT][TS + LP];
    const int tid = threadIdx.x;
    const int tx = tid & 15, ty = tid >> 4;
    const int mBase = blockIdx.y * TS;
    const int nBase = blockIdx.x * TS;

    float acc[4][4] = {};
    const int ar = tid >> 2;
    const int ak = (tid & 3) * 4;

    for (int kb = 0; kb < DT_RANK; kb += KT) {
        {
            const float4 av = *(const float4*)&A[(size_t)(mBase + ar) * DT_RANK + kb + ak];
            As[ak + 0][ar] = av.x;
            As[ak + 1][ar] = av.y;
            As[ak + 2][ar] = av.z;
            As[ak + 3][ar] = av.w;
        }
        {
            const float4 bv = *(const float4*)&B[(size_t)(nBase + ar) * 96 + kb + ak];
            Bs[ak + 0][ar] = bv.x;
            Bs[ak + 1][ar] = bv.y;
            Bs[ak + 2][ar] = bv.z;
            Bs[ak + 3][ar] = bv.w;
        }
        __syncthreads();
        #pragma unroll
        for (int k = 0; k < KT; ++k) {
            float4 a = *(const float4*)&As[k][ty * 4];
            float4 b = *(const float4*)&Bs[k][tx * 4];
            float av[4] = {a.x, a.y, a.z, a.w};
            float bv[4] = {b.x, b.y, b.z, b.w};
            #pragma unroll
            for (int i = 0; i < 4; ++i)
                #pragma unroll
                for (int j = 0; j < 4; ++j)
                    acc[i][j] = fmaf(av[i], bv[j], acc[i][j]);
        }
        __syncthreads();
    }

    #pragma unroll
    for (int i = 0; i < 4; ++i)
        #pragma unroll
        for (int j = 0; j < 4; ++j)
            C[(size_t)(mBase + ty * 4 + i) * LSEQ + nBase + tx * 4 + j] = softplus_f(acc[i][j]);
}

// ---------------- depthwise causal conv1d + SiLU ----------------
__global__ __launch_bounds__(256)
void conv_silu_k(const float* __restrict__ xa, const float* __restrict__ x1p,
                 const float* __restrict__ w0, const float* __restrict__ b0,
                 const float* __restrict__ w1, const float* __restrict__ b1,
                 float* __restrict__ co0, float* __restrict__ co1)
{
    const int idx = blockIdx.x * blockDim.x + threadIdx.x;
    const int br  = idx >> 21;
    const int rem = idx & ((1 << 21) - 1);
    const int d = rem >> 10;
    const int l = rem & (LSEQ - 1);

    const float* xin = br ? x1p : xa;
    const float* w   = br ? w1 : w0;
    const float* bb  = br ? b1 : b0;
    float* out       = br ? co1 : co0;

    const float* row = xin + (size_t)d * LSEQ;
    float acc = bb[d];
    #pragma unroll
    for (int j = 0; j < D_CONV; ++j) {
        const int li = l - (D_CONV - 1) + j;
        const float xv = (li >= 0) ? row[li] : 0.f;
        acc = fmaf(w[d * D_CONV + j], xv, acc);
    }
    out[rem] = silu_f(acc);
}

// ---------------- chunk-parallel selective scan: 4 ch/block, 512 thr (32c x 16n) ----------------
// grid (D_INNER/4, 2) = 1024 blocks x 8 waves = 8192 waves -> 100% machine fill.
// Each thread runs 4 independent channel chains over a 32-step chunk; bc loads shared.
__global__ __launch_bounds__(512)
void scan7_k(const float* __restrict__ sp0, const float* __restrict__ u0,
             const float* __restrict__ xdT0,
             const float* __restrict__ Al0, const float* __restrict__ Dk0,
             const float* __restrict__ sp1, const float* __restrict__ u1,
             const float* __restrict__ xdT1,
             const float* __restrict__ Al1, const float* __restrict__ Dk1,
             const float* __restrict__ gz,
             float* __restrict__ res0, float* __restrict__ res1)
{
    const int d0  = blockIdx.x * 4;
    const int br  = blockIdx.y;
    const int tid = threadIdx.x;
    const int n   = tid & 15;
    const int c   = tid >> 4;          // 0..31

    const float* __restrict__ sp  = br ? sp1  : sp0;
    const float* __restrict__ u   = br ? u1   : u0;
    const float* __restrict__ xdT = br ? xdT1 : xdT0;
    const float* __restrict__ Al  = br ? Al1  : Al0;
    const float* __restrict__ Dk  = br ? Dk1  : Dk0;
    float* __restrict__ res       = br ? res1 : res0;

    float Adn[4], Dd[4];
    const float* srow[4]; const float* urow[4]; const float* grow[4]; float* orow[4];
    #pragma unroll
    for (int g = 0; g < 4; ++g) {
        Adn[g] = -__expf(Al[(d0 + g) * D_STATE + n]);
        Dd[g]  = Dk[d0 + g];
        srow[g] = sp + (size_t)(d0 + g) * LSEQ;
        urow[g] = u  + (size_t)(d0 + g) * LSEQ;
        grow[g] = gz + (size_t)(d0 + g) * LSEQ;
        orow[g] = res + (size_t)(d0 + g) * LSEQ;
    }
    const float* __restrict__ bc = xdT + 64 + 2 * n;
    const int t0 = c * 32;

    // ---- phase 1: chunk-local (a, b) per channel
    float a[4] = {1.f, 1.f, 1.f, 1.f};
    float b[4] = {0.f, 0.f, 0.f, 0.f};
    for (int tt = 0; tt < 32; tt += 4) {
        float2 bcv[4];
        #pragma unroll
        for (int j = 0; j < 4; ++j)
            bcv[j] = *(const float2*)&bc[(size_t)(t0 + tt + j) * 96];
        #pragma unroll
        for (int g = 0; g < 4; ++g) {
            const float4 s4 = *(const float4*)&srow[g][t0 + tt];
            const float4 u4 = *(const float4*)&urow[g][t0 + tt];
            const float sps[4] = {s4.x, s4.y, s4.z, s4.w};
            const float uvs[4] = {u4.x, u4.y, u4.z, u4.w};
            #pragma unroll
            for (int j = 0; j < 4; ++j) {
                const float dA = __expf(sps[j] * Adn[g]);
                a[g] *= dA;
                b[g] = fmaf(dA, b[g], sps[j] * uvs[j] * bcv[j].x);
            }
        }
    }

    __shared__ float sAm[32][16][4];
    __shared__ float sBm[32][16][4];
    __shared__ float sHm[32][16][4];
    #pragma unroll
    for (int g = 0; g < 4; ++g) { sAm[c][n][g] = a[g]; sBm[c][n][g] = b[g]; }
    __syncthreads();

    // ---- phase 2: serial exclusive scan over 32 chunks (64 threads: one per (n, g))
    if (tid < 64) {
        const int n2 = tid & 15, g2 = tid >> 4;
        float hb = 0.f;
        #pragma unroll
        for (int cc = 0; cc < 32; ++cc) {
            sHm[cc][n2][g2] = hb;
            hb = fmaf(sAm[cc][n2][g2], hb, sBm[cc][n2][g2]);
        }
    }
    __syncthreads();

    // ---- phase 3: re-run chunk from h_start, emit y
    float h[4];
    #pragma unroll
    for (int g = 0; g < 4; ++g) h[g] = sHm[c][n][g];

    for (int tt = 0; tt < 32; tt += 4) {
        float2 bcv[4];
        #pragma unroll
        for (int j = 0; j < 4; ++j)
            bcv[j] = *(const float2*)&bc[(size_t)(t0 + tt + j) * 96];
        #pragma unroll
        for (int g = 0; g < 4; ++g) {
            const float4 s4 = *(const float4*)&srow[g][t0 + tt];
            const float4 u4 = *(const float4*)&urow[g][t0 + tt];
            const float4 g4 = *(const float4*)&grow[g][t0 + tt];
            const float sps[4] = {s4.x, s4.y, s4.z, s4.w};
            const float uvs[4] = {u4.x, u4.y, u4.z, u4.w};
            const float gzs[4] = {g4.x, g4.y, g4.z, g4.w};
            float y4[4];
            #pragma unroll
            for (int j = 0; j < 4; ++j) {
                const float dA = __expf(sps[j] * Adn[g]);
                h[g] = fmaf(dA, h[g], sps[j] * uvs[j] * bcv[j].x);
                float y = h[g] * bcv[j].y;
                y += __shfl_xor(y, 1);
                y += __shfl_xor(y, 2);
                y += __shfl_xor(y, 4);
                y += __shfl_xor(y, 8);
                y4[j] = y;
            }
            if (n == 0) {
                float4 o;
                float* op = (float*)&o;
                #pragma unroll
                for (int j = 0; j < 4; ++j)
                    op[j] = (y4[j] + Dd[g] * uvs[j]) * gzs[j];
                *(float4*)&orow[g][t0 + tt] = o;
            }
        }
    }
}

// ---------------- launcher ----------------
extern "C" void kernel_launch(void* const* d_in, const int* in_sizes, int n_in,
                              void* d_out, int out_size, void* d_ws, size_t ws_size,
                              hipStream_t stream)
{
    const float* x          = (const float*)d_in[0];
    const float* x1         = (const float*)d_in[1];
    const float* in_proj_w  = (const float*)d_in[2];
    const float* in_proj1_w = (const float*)d_in[3];
    const float* conv_w     = (const float*)d_in[4];
    const float* conv_b     = (const float*)d_in[5];
    const float* conv1_w    = (const float*)d_in[6];
    const float* conv1_b    = (const float*)d_in[7];
    const float* x_proj_w   = (const float*)d_in[8];
    const float* x_proj1_w  = (const float*)d_in[9];
    const float* dt_proj_w  = (const float*)d_in[10];
    const float* dt_proj1_w = (const float*)d_in[11];
    const float* A_log      = (const float*)d_in[12];
    const float* A_log1     = (const float*)d_in[13];
    const float* Dskip      = (const float*)d_in[14];
    const float* Dskip1     = (const float*)d_in[15];
    const float* out_proj_w = (const float*)d_in[16];

    float* ws = (float*)d_ws;
    const size_t CH = (size_t)D_INNER * LSEQ;
    const size_t XD = (size_t)96 * LSEQ;
    const size_t F  = 5 * CH + 2 * XD;

    float* XA    = ws;
    float* RES0  = ws;                   // over dead xa
    float* GZ    = ws + CH;
    float* X1P   = ws + 2 * CH;
    float* RES1  = ws + 2 * CH;          // over dead x1p
    float* CO0   = ws + 3 * CH;
    float* CO1   = ws + 4 * CH;
    float* XDT0  = ws + 5 * CH;
    float* XDT1  = XDT0 + XD;
    float* XZ    = ws;

    unsigned short* WB  = (unsigned short*)(ws + F);
    unsigned short* XB  = (unsigned short*)(ws + F + 2097152);
    unsigned short* WB1 = (unsigned short*)(ws + F + 2097152 + 524288);
    unsigned short* X1B = (unsigned short*)(ws + F + 2097152 + 524288 + 1048576);
    float* P0  = ws + F;
    float* P1  = P0 + 8 * XD;
    float* SP0 = ws + F;
    float* SP1 = ws + F + CH;
    unsigned short* OWB   = (unsigned short*)(ws + F);
    unsigned short* RESTB = (unsigned short*)(ws + F + CH / 2);

    float* out = (float*)d_out;

    // 1) convert all four GEMM inputs to bf16
    hipLaunchKernelGGL(cvt_all_k, dim3((2 << 20) / 256), dim3(256), 0, stream,
                       in_proj_w, x, in_proj1_w, x1, WB, XB, WB1, X1B);

    // 2) in_proj + in_proj1 (merged bf16 MFMA); z rows get silu
    hipLaunchKernelGGL(mfma_in_k, dim3(8, 48), dim3(256), 0, stream,
                       WB, XB, WB1, X1B, XZ, X1P);

    // 3) causal conv + silu
    hipLaunchKernelGGL(conv_silu_k, dim3(2 * D_INNER * LSEQ / 256), dim3(256), 0, stream,
                       XA, X1P, conv_w, conv_b, conv1_w, conv1_b, CO0, CO1);

    // 4) x_proj split-K (one launch, 512 blocks)
    hipLaunchKernelGGL(xproj_k, dim3(LSEQ / TS, 2, 16), dim3(256), 0, stream,
                       x_proj_w, CO0, x_proj1_w, CO1, P0, P1);

    // 5) reduce partials -> xdT [L][96] interleaved
    hipLaunchKernelGGL(reduceT_k, dim3(2 * LSEQ * 128 / 256), dim3(256), 0, stream,
                       P0, P1, XDT0, XDT1);

    // 6) dt_proj (both branches) + fused softplus -> SP
    hipLaunchKernelGGL(dtproj_k, dim3(LSEQ / TS, D_INNER / TS, 2), dim3(256), 0, stream,
                       dt_proj_w, XDT0, dt_proj1_w, XDT1, SP0, SP1);

    // 7) chunk-parallel scan, 4 ch/block, 512 threads, full machine fill
    hipLaunchKernelGGL(scan7_k, dim3(D_INNER / 4, 2), dim3(512), 0, stream,
                       SP0, CO0, XDT0, A_log, Dskip,
                       SP1, CO1, XDT1, A_log1, Dskip1,
                       GZ, RES0, RES1);

    // 8) OWB = bf16(out_proj_w); REST[l,d] = bf16(res0+res1)
    hipLaunchKernelGGL(cvt_k, dim3((1024 * 2048 / 4) / 256), dim3(256), 0, stream,
                       out_proj_w, OWB, 1024 * 2048 / 4);
    hipLaunchKernelGGL(cvtT_add_k, dim3(LSEQ / 32, D_INNER / 32), dim3(256), 0, stream,
                       RES0, RES1, RESTB);

    // 9) out_proj (bf16 MFMA)
    hipLaunchKernelGGL(mfma_out_k, dim3(8, 8), dim3(256), 0, stream,
                       RESTB, OWB, out);
}